// Round 7
// baseline (253.779 us; speedup 1.0000x reference)
//
#include <hip/hip_runtime.h>
#include <math.h>

// Problem constants: B=4, S=1024, DIM=1280, H=16, HD=80
// Inputs fp32 (runtime-probed); OUTPUT FP32.
#define SCALE_F 0.11180339887498949f   // 80^-0.5
#define HDP 96                          // HD padded to multiple of 32 for QK^T

typedef short  short8  __attribute__((ext_vector_type(8)));
typedef short  short4v __attribute__((ext_vector_type(4)));
typedef float  f32x4   __attribute__((ext_vector_type(4)));
typedef __bf16 bf16x8  __attribute__((ext_vector_type(8)));

__device__ __forceinline__ float bf2f(short s) {
  union { unsigned u; float f; } v;
  v.u = ((unsigned)(unsigned short)s) << 16;
  return v.f;
}
__device__ __forceinline__ short f2b(float f) {
  __bf16 h = (__bf16)f;
  return __builtin_bit_cast(short, h);
}
__device__ __forceinline__ bool probe_is_bf16(const unsigned* probe) {
  return (probe[1] & 0xFFFFu) != 0u;
}
__device__ __forceinline__ float load_scalar(const void* p, int i, bool isb) {
  return isb ? bf2f(((const short*)p)[i]) : ((const float*)p)[i];
}

// async global->LDS, 16B per lane. HW LDS placement: wave-uniform base +
// lane*16 (m104/m108); per-lane pointer below coincides with that exactly.
__device__ __forceinline__ void gload_lds16(const short* g, short* l) {
  __builtin_amdgcn_global_load_lds(
      (const __attribute__((address_space(1))) void*)g,
      (__attribute__((address_space(3))) void*)l, 16, 0, 0);
}

template <typename V>
__device__ __forceinline__ auto mfma_try(V a, V b, f32x4 c, int)
    -> decltype(__builtin_amdgcn_mfma_f32_16x16x32_bf16(a, b, c, 0, 0, 0)) {
  return __builtin_amdgcn_mfma_f32_16x16x32_bf16(a, b, c, 0, 0, 0);
}
template <typename V>
__device__ __forceinline__ f32x4 mfma_try(V a, V b, f32x4 c, long) {
  return __builtin_amdgcn_mfma_f32_16x16x32_bf16(
      __builtin_bit_cast(bf16x8, a), __builtin_bit_cast(bf16x8, b), c, 0, 0, 0);
}
__device__ __forceinline__ f32x4 MFMA(short8 a, short8 b, f32x4 c) {
  return mfma_try(a, b, c, 0);
}

// ------------------------------------------------------- canonicalize: x->bf16
__global__ __launch_bounds__(256) void cvt_x_kernel(
    const void* __restrict__ xin, short* __restrict__ xout,
    const unsigned* __restrict__ probe) {
  bool isb = probe_is_bf16(probe);
  size_t i = ((size_t)blockIdx.x * 256 + threadIdx.x) * 8;
  if (isb) {
    *(short8*)&xout[i] = *(const short8*)((const short*)xin + i);
  } else {
    const float* f = (const float*)xin + i;
    float4 a0 = *(const float4*)f;
    float4 a1 = *(const float4*)(f + 4);
    short8 sv;
    sv[0] = f2b(a0.x); sv[1] = f2b(a0.y); sv[2] = f2b(a0.z); sv[3] = f2b(a0.w);
    sv[4] = f2b(a1.x); sv[5] = f2b(a1.y); sv[6] = f2b(a1.z); sv[7] = f2b(a1.w);
    *(short8*)&xout[i] = sv;
  }
}

// ---------------------------------------------------------------- transpose
__global__ __launch_bounds__(256) void transpose_kernel(
    const void* __restrict__ in, short* __restrict__ out, int R, int C,
    const unsigned* __restrict__ probe) {
  bool isb = probe_is_bf16(probe);
  __shared__ float tile[32][33];
  int t = threadIdx.x;
  int bx = blockIdx.x;  // over C
  int by = blockIdx.y;  // over R
  int r = t >> 3, c4 = (t & 7) * 4;
  size_t idx = (size_t)(by * 32 + r) * C + bx * 32 + c4;
  if (isb) {
    short4v v = *(const short4v*)((const short*)in + idx);
    tile[r][c4 + 0] = bf2f(v[0]);
    tile[r][c4 + 1] = bf2f(v[1]);
    tile[r][c4 + 2] = bf2f(v[2]);
    tile[r][c4 + 3] = bf2f(v[3]);
  } else {
    float4 v = *(const float4*)((const float*)in + idx);
    tile[r][c4 + 0] = v.x;
    tile[r][c4 + 1] = v.y;
    tile[r][c4 + 2] = v.z;
    tile[r][c4 + 3] = v.w;
  }
  __syncthreads();
  int rr = t >> 3, k4 = (t & 7) * 4;
  short4v o;
  o[0] = f2b(tile[k4 + 0][rr]);
  o[1] = f2b(tile[k4 + 1][rr]);
  o[2] = f2b(tile[k4 + 2][rr]);
  o[3] = f2b(tile[k4 + 3][rr]);
  *(short4v*)&out[(size_t)(bx * 32 + rr) * R + by * 32 + k4] = o;
}

// ---------------------------------------------------------------- QKV GEMM
// r7: LDS-read-bound fix. Wave tile 128x64 (2M x 4N wave grid): per phase
// 12 ds_read_b128 feed 32 MFMA (was 12:16) -> LDS 1152 cyc ~ MFMA 1242 cyc
// per CU per phase, balanced. BK=32, 4-slot LDS ring (4 x 256x32 x A,B =
// 128 KiB), prefetch distance 3 phases, uniform vmcnt(8); tail stages are
// dummies into dead slots to keep vmcnt accounting exact. Swizzle for 64B
// row stride: kchunk ^= (row>>1)&3 -- each consecutive-8 lane group of a
// b128 read covers all 32 banks once (same property as the r5 swizzle that
// measured 0 conflicts).
__global__ __launch_bounds__(512, 2) void gemm_qkv_kernel(
    const short* __restrict__ X, const short* __restrict__ Wt,
    const void* __restrict__ bias, const unsigned* __restrict__ probe,
    short* __restrict__ Qw, short* __restrict__ Kw, short* __restrict__ Vt) {
  __shared__ short Asl[4][8192];   // [slot][256 rows x 32 k]
  __shared__ short Bsl[4][8192];
  int t = threadIdx.x;
  int bm = blockIdx.x / 15, bn = blockIdx.x % 15;
  int m0 = bm * 256, n0 = bn * 256;
  int w = t >> 6, lane = t & 63;
  int quad = lane >> 4, l16 = lane & 15;
  int wm = w >> 2, wn = w & 3;          // wave tile: rows wm*128.., cols wn*64..
  int arow = wm * 128 + l16;            // + mt*16
  int brow = wn * 64 + l16;             // + nt*16
  int qsw8 = (quad ^ ((l16 >> 1) & 3)) * 8;   // swizzled k-chunk (elements)
  // staging: thread t covers 16B-slots t (row t>>2) and t+512 (row +128)
  int srow = t >> 2, t8s = t * 8;
  int sks = (t & 3) ^ ((srow >> 1) & 3);      // pre-swizzled global k-chunk
  f32x4 acc[8][4] = {};                  // [mt][nt], all-static indexing

#define STAGE32(KT)                                                          \
  {                                                                          \
    int kn_ = (KT);                                                          \
    int koff_ = (kn_ < 40) ? kn_ * 32 : 0;  /* dummy into dead slot */       \
    int Sd_ = kn_ & 3;                                                       \
    const short* ga_ = X + (size_t)(m0 + srow) * 1280 + koff_ + sks * 8;     \
    gload_lds16(ga_, &Asl[Sd_][t8s]);                                        \
    gload_lds16(ga_ + 128 * 1280, &Asl[Sd_][t8s + 4096]);                    \
    const short* gb_ = Wt + (size_t)(n0 + srow) * 1280 + koff_ + sks * 8;    \
    gload_lds16(gb_, &Bsl[Sd_][t8s]);                                        \
    gload_lds16(gb_ + 128 * 1280, &Bsl[Sd_][t8s + 4096]);                    \
  }

  // prologue: stage kt 0,1,2 (12 loads/thread); kt0 landed at vmcnt(8)
  STAGE32(0);
  STAGE32(1);
  STAGE32(2);
  asm volatile("s_waitcnt vmcnt(8)" ::: "memory");
  __builtin_amdgcn_sched_barrier(0);
  __builtin_amdgcn_s_barrier();

  for (int kt = 0; kt < 40; kt++) {
    int S = kt & 3;
    const short* As = &Asl[S][0];
    const short* Bs = &Bsl[S][0];
    STAGE32(kt + 3);                     // in-flight slots never alias S
    short8 af[8], bfv[4];
#pragma unroll
    for (int mt = 0; mt < 8; mt++)
      af[mt] = *(const short8*)&As[(arow + mt * 16) * 32 + qsw8];
#pragma unroll
    for (int nt = 0; nt < 4; nt++)
      bfv[nt] = *(const short8*)&Bs[(brow + nt * 16) * 32 + qsw8];
    asm volatile("s_waitcnt lgkmcnt(0)" ::: "memory");
    __builtin_amdgcn_sched_barrier(0);
    __builtin_amdgcn_s_setprio(1);
#pragma unroll
    for (int mt = 0; mt < 8; mt++)
#pragma unroll
      for (int nt = 0; nt < 4; nt++)
        acc[mt][nt] = MFMA(af[mt], bfv[nt], acc[mt][nt]);
    __builtin_amdgcn_s_setprio(0);
    asm volatile("s_waitcnt vmcnt(8)" ::: "memory");   // kt+1 fully landed
    __builtin_amdgcn_sched_barrier(0);
    __builtin_amdgcn_s_barrier();
  }
  asm volatile("s_waitcnt vmcnt(0)" ::: "memory");     // drain dummy stages
  __builtin_amdgcn_sched_barrier(0);

  bool isb = probe_is_bf16(probe);
  float bv[4];
#pragma unroll
  for (int nt = 0; nt < 4; nt++)
    bv[nt] = load_scalar(bias, n0 + wn * 64 + nt * 16 + l16, isb);
#pragma unroll
  for (int mt = 0; mt < 8; mt++) {
    int mbase = m0 + wm * 128 + mt * 16 + quad * 4;
    int b = mbase >> 10, sbase = mbase & 1023;
#pragma unroll
    for (int nt = 0; nt < 4; nt++) {
      int n = n0 + wn * 64 + nt * 16 + l16;
      int which = n / 1280;
      int rmod = n - which * 1280;
      int h = rmod / 80;
      int d = rmod - h * 80;
      int bh = b * 16 + h;
      if (which == 2) {
        short4v vv;
#pragma unroll
        for (int reg = 0; reg < 4; reg++)
          vv[reg] = f2b(acc[mt][nt][reg] + bv[nt]);
        *(short4v*)&Vt[((size_t)bh * 80 + d) * 1024 + sbase] = vv;
      } else {
        short* dst = (which == 0 ? Qw : Kw);
#pragma unroll
        for (int reg = 0; reg < 4; reg++)
          dst[((size_t)bh * 1024 + sbase + reg) * HDP + d] =
              f2b(acc[mt][nt][reg] + bv[nt]);
      }
    }
  }
#undef STAGE32
}

// ---------------------------------------------------------------- RoPE
__global__ __launch_bounds__(256) void rope_kernel(
    short* __restrict__ Qw, short* __restrict__ Kw,
    const void* __restrict__ cosb, const void* __restrict__ sinb,
    const unsigned* __restrict__ probe) {
  bool isb = probe_is_bf16(probe);
  int t = threadIdx.x;
  int w = t >> 6, lane = t & 63;
  int job = blockIdx.x * 4 + w;   // 64*1024*2 jobs
  int which = job & 1;
  int row = job >> 1;             // bh*1024 + s
  int s = row & 1023;
  short* ptr = (which ? Kw : Qw) + (size_t)row * HDP;
  float scale = which ? 1.0f : SCALE_F;
  if (lane < 40) {
    float p0 = bf2f(ptr[lane]);
    float p1 = bf2f(ptr[lane + 40]);
    float c0 = load_scalar(cosb, s * 80 + lane, isb);
    float s0 = load_scalar(sinb, s * 80 + lane, isb);
    float c1 = load_scalar(cosb, s * 80 + lane + 40, isb);
    float s1 = load_scalar(sinb, s * 80 + lane + 40, isb);
    ptr[lane] = f2b((p0 * c0 - p1 * s0) * scale);
    ptr[lane + 40] = f2b((p1 * c1 + p0 * s1) * scale);
  } else if (lane < 56) {
    ptr[40 + lane] = 0;  // d = 80..95
  }
}

// ---------------------------------------------------------------- attention
// 8 waves / 128 q-rows per block; double-buffered K/V LDS, one barrier per
// chunk (verified r6).
__global__ __launch_bounds__(512, 4) void attn_kernel(
    const short* __restrict__ Qw, const short* __restrict__ Kw,
    const short* __restrict__ Vt, short* __restrict__ out) {
  __shared__ short Klds[2][64 * 104];
  __shared__ short Vlds[2][80 * 72];
  __shared__ short Ps[8][16 * 72];
  int t = threadIdx.x;
  int w = t >> 6, lane = t & 63;
  int quad = lane >> 4, l16 = lane & 15;
  int bh = blockIdx.x & 63;        // XCD swizzle: same bh -> same XCD
  int qt = blockIdx.x >> 6;        // 0..3
  int q0 = qt * 128;
  const short* Kb = Kw + (size_t)bh * 1024 * HDP;
  const short* Vb = Vt + (size_t)bh * 80 * 1024;

  // Q fragments (pre-scaled by SCALE_F in rope), one-time global read
  short8 aq[3];
  {
    const short* qrow = Qw + ((size_t)bh * 1024 + q0 + w * 16 + l16) * HDP;
#pragma unroll
    for (int ks = 0; ks < 3; ks++)
      aq[ks] = *(const short8*)&qrow[ks * 32 + quad * 8];
  }

  // staging with 512 threads: K 64x96 = 768 slots; V 80x64 = 640 slots
  short8 kreg[2], vreg[2];
#define PREFETCH(c)                                                        \
  {                                                                        \
    {                                                                      \
      int row = t / 12, col = (t % 12) * 8;                                \
      kreg[0] = *(const short8*)&Kb[(size_t)((c) + row) * HDP + col];      \
    }                                                                      \
    if (t < 256) {                                                         \
      int idx = 512 + t;                                                   \
      int row = idx / 12, col = (idx % 12) * 8;                            \
      kreg[1] = *(const short8*)&Kb[(size_t)((c) + row) * HDP + col];      \
    }                                                                      \
    {                                                                      \
      int d = t >> 3, s0 = (t & 7) * 8;                                    \
      vreg[0] = *(const short8*)&Vb[(size_t)d * 1024 + (c) + s0];          \
    }                                                                      \
    if (t < 128) {                                                         \
      int idx = 512 + t;                                                   \
      int d = idx >> 3, s0 = (idx & 7) * 8;                                \
      vreg[1] = *(const short8*)&Vb[(size_t)d * 1024 + (c) + s0];          \
    }                                                                      \
  }
#define STORE_LDS(P)                                                       \
  {                                                                        \
    {                                                                      \
      int row = t / 12, col = (t % 12) * 8;                                \
      *(short8*)&Klds[P][row * 104 + col] = kreg[0];                       \
    }                                                                      \
    if (t < 256) {                                                         \
      int idx = 512 + t;                                                   \
      int row = idx / 12, col = (idx % 12) * 8;                            \
      *(short8*)&Klds[P][row * 104 + col] = kreg[1];                       \
    }                                                                      \
    {                                                                      \
      int d = t >> 3, s0 = (t & 7) * 8;                                    \
      *(short8*)&Vlds[P][d * 72 + s0] = vreg[0];                           \
    }                                                                      \
    if (t < 128) {                                                         \
      int idx = 512 + t;                                                   \
      int d = idx >> 3, s0 = (idx & 7) * 8;                                \
      *(short8*)&Vlds[P][d * 72 + s0] = vreg[1];                           \
    }                                                                      \
  }

  PREFETCH(0);
  STORE_LDS(0);
  __syncthreads();

  f32x4 ofr[5] = {};
  float lsum[4] = {0.f, 0.f, 0.f, 0.f};
  short* Pw = &Ps[w][0];

  int p = 0;
  for (int c = 0; c < 1024; c += 64, p ^= 1) {
    if (c + 64 < 1024) PREFETCH(c + 64);   // global loads fly under compute
    const short* Kl = &Klds[p][0];
    const short* Vl = &Vlds[p][0];
    // QK^T chunk from LDS: S(16x64) per wave
    f32x4 sf[4] = {};
#pragma unroll
    for (int nt = 0; nt < 4; nt++) {
      short8 bk0 = *(const short8*)&Kl[(nt * 16 + l16) * 104 + 0 * 32 + quad * 8];
      short8 bk1 = *(const short8*)&Kl[(nt * 16 + l16) * 104 + 1 * 32 + quad * 8];
      short8 bk2 = *(const short8*)&Kl[(nt * 16 + l16) * 104 + 2 * 32 + quad * 8];
      sf[nt] = MFMA(aq[0], bk0, sf[nt]);
      sf[nt] = MFMA(aq[1], bk1, sf[nt]);
      sf[nt] = MFMA(aq[2], bk2, sf[nt]);
    }
    // unsafe softmax: p = exp(min(s,30)); per-lane partial row sums only
#pragma unroll
    for (int r = 0; r < 4; r++) {
      float p0 = __expf(fminf(sf[0][r], 30.f));
      float p1 = __expf(fminf(sf[1][r], 30.f));
      float p2 = __expf(fminf(sf[2][r], 30.f));
      float p3 = __expf(fminf(sf[3][r], 30.f));
      sf[0][r] = p0; sf[1][r] = p1; sf[2][r] = p2; sf[3][r] = p3;
      lsum[r] += (p0 + p1) + (p2 + p3);
    }
    // P -> per-wave LDS (C-layout -> A-layout); DS in-order within wave
#pragma unroll
    for (int nt = 0; nt < 4; nt++)
#pragma unroll
      for (int r = 0; r < 4; r++)
        Pw[(quad * 4 + r) * 72 + nt * 16 + l16] = f2b(sf[nt][r]);
    __threadfence_block();
    short8 ap[2];
#pragma unroll
    for (int ks = 0; ks < 2; ks++)
      ap[ks] = *(const short8*)&Pw[l16 * 72 + ks * 32 + quad * 8];
    // PV from LDS V tile
#pragma unroll
    for (int nt = 0; nt < 5; nt++) {
      short8 bv0 = *(const short8*)&Vl[(nt * 16 + l16) * 72 + 0 * 32 + quad * 8];
      short8 bv1 = *(const short8*)&Vl[(nt * 16 + l16) * 72 + 1 * 32 + quad * 8];
      ofr[nt] = MFMA(ap[0], bv0, ofr[nt]);
      ofr[nt] = MFMA(ap[1], bv1, ofr[nt]);
    }
    if (c + 64 < 1024) {
      STORE_LDS(p ^ 1);       // idle buffer; readers of it passed last barrier
      __syncthreads();        // publish + close this iter's reads of buf p
    }
  }
  // single end-of-kernel reduction: row sums across the 16-lane groups
#pragma unroll
  for (int off = 1; off < 16; off <<= 1)
#pragma unroll
    for (int r = 0; r < 4; r++) lsum[r] += __shfl_xor(lsum[r], off);
  float inv[4];
#pragma unroll
  for (int r = 0; r < 4; r++) inv[r] = 1.f / lsum[r];
  int b = bh >> 4, h = bh & 15;
#pragma unroll
  for (int nt = 0; nt < 5; nt++) {
    int d = nt * 16 + l16;
#pragma unroll
    for (int r = 0; r < 4; r++) {
      int s = q0 + w * 16 + quad * 4 + r;
      out[((size_t)(b * 1024 + s)) * 1280 + h * 80 + d] = f2b(ofr[nt][r] * inv[r]);
    }
  }
}

// ---------------------------------------------------------------- proj GEMM
__global__ __launch_bounds__(256) void gemm_proj_kernel(
    const short* __restrict__ A, const short* __restrict__ Wt,
    const void* __restrict__ bias, const unsigned* __restrict__ probe,
    float* __restrict__ out) {
  const int K = 1280;
  __shared__ short As[2][128 * 32];
  __shared__ short Bs[2][128 * 32];
  int t = threadIdx.x;
  int bm = blockIdx.x / 10;
  int bn = blockIdx.x % 10;
  int m0 = bm * 128, n0 = bn * 128;
  int w = t >> 6, lane = t & 63;
  int wm = w & 1, wn = w >> 1;
  int quad = lane >> 4, l16 = lane & 15;
  int row = t >> 2, ch = (t & 3) * 8, row2 = row + 64;
  int t8 = t * 8;
  const short* Ar  = A  + (size_t)(m0 + row)  * K + ch;
  const short* Ar2 = A  + (size_t)(m0 + row2) * K + ch;
  const short* Wr  = Wt + (size_t)(n0 + row)  * K + ch;
  const short* Wr2 = Wt + (size_t)(n0 + row2) * K + ch;
  f32x4 acc[4][4] = {};
  gload_lds16(Ar,  &As[0][t8]);
  gload_lds16(Ar2, &As[0][t8 + 2048]);
  gload_lds16(Wr,  &Bs[0][t8]);
  gload_lds16(Wr2, &Bs[0][t8 + 2048]);
  __syncthreads();
  int p = 0;
#define PROJ_COMPUTE(pp)                                                      \
  {                                                                           \
    short8 af[4], bfr[4];                                                     \
    _Pragma("unroll") for (int mt = 0; mt < 4; mt++)                          \
        af[mt] = *(const short8*)&As[pp][(wm * 64 + mt * 16 + l16) * 32 + quad * 8]; \
    _Pragma("unroll") for (int nt = 0; nt < 4; nt++)                          \
        bfr[nt] = *(const short8*)&Bs[pp][(wn * 64 + nt * 16 + l16) * 32 + quad * 8]; \
    _Pragma("unroll") for (int mt = 0; mt < 4; mt++)                          \
        _Pragma("unroll") for (int nt = 0; nt < 4; nt++)                      \
            acc[mt][nt] = MFMA(af[mt], bfr[nt], acc[mt][nt]);                 \
  }
  for (int k0 = 32; k0 < K; k0 += 32, p ^= 1) {
    gload_lds16(Ar + k0,  &As[p ^ 1][t8]);
    gload_lds16(Ar2 + k0, &As[p ^ 1][t8 + 2048]);
    gload_lds16(Wr + k0,  &Bs[p ^ 1][t8]);
    gload_lds16(Wr2 + k0, &Bs[p ^ 1][t8 + 2048]);
    PROJ_COMPUTE(p);
    __syncthreads();
  }
  PROJ_COMPUTE(p);
  bool isb = probe_is_bf16(probe);
  float bv[4];
#pragma unroll
  for (int nt = 0; nt < 4; nt++)
    bv[nt] = load_scalar(bias, n0 + wn * 64 + nt * 16 + l16, isb);
#pragma unroll
  for (int mt = 0; mt < 4; mt++) {
#pragma unroll
    for (int nt = 0; nt < 4; nt++) {
      int n = n0 + wn * 64 + nt * 16 + l16;
#pragma unroll
      for (int reg = 0; reg < 4; reg++) {
        int m = m0 + wm * 64 + mt * 16 + quad * 4 + reg;
        out[(size_t)m * 1280 + n] = acc[mt][nt][reg] + bv[nt];  // FP32 store
      }
    }
  }
}

extern "C" void kernel_launch(void* const* d_in, const int* in_sizes, int n_in,
                              void* d_out, int out_size, void* d_ws, size_t ws_size,
                              hipStream_t stream) {
  const void* x        = d_in[0];
  const void* rope_cos = d_in[1];
  const void* rope_sin = d_in[2];
  const void* Wqkv     = d_in[3];
  const void* bqkv     = d_in[4];
  const void* Wproj    = d_in[5];
  const void* bproj    = d_in[6];
  const unsigned* probe = (const unsigned*)rope_cos;
  char* ws = (char*)d_ws;
  short* Wt1 = (short*)(ws + 0);          // 1280*3840*2 = 9,830,400
  short* Wt2 = (short*)(ws + 9830400);    // 1280*1280*2 = 3,276,800
  short* Qw  = (short*)(ws + 13107200);   // 64*1024*96*2 = 12,582,912
  short* Kw  = (short*)(ws + 25690112);   // 12,582,912
  short* Vt  = (short*)(ws + 38273024);   // 64*1024*80*2 = 10,485,760
  short* Xb  = (short*)(ws + 48758784);   // 4096*1280*2 = 10,485,760
  short* At  = (short*)(ws + 48758784);   // aliases Xb (disjoint lifetimes)

  cvt_x_kernel<<<2560, 256, 0, stream>>>(x, Xb, probe);
  transpose_kernel<<<dim3(3840 / 32, 1280 / 32), 256, 0, stream>>>(Wqkv, Wt1, 1280, 3840, probe);
  transpose_kernel<<<dim3(1280 / 32, 1280 / 32), 256, 0, stream>>>(Wproj, Wt2, 1280, 1280, probe);
  gemm_qkv_kernel<<<240, 512, 0, stream>>>(Xb, Wt1, bqkv, probe, Qw, Kw, Vt);
  rope_kernel<<<32768, 256, 0, stream>>>(Qw, Kw, rope_cos, rope_sin, probe);
  attn_kernel<<<512, 512, 0, stream>>>(Qw, Kw, Vt, At);
  gemm_proj_kernel<<<32 * 10, 256, 0, stream>>>(At, Wt2, bproj, probe, (float*)d_out);
}

// Round 8
// 244.228 us; speedup vs baseline: 1.0391x; 1.0391x over previous
//
#include <hip/hip_runtime.h>
#include <math.h>

// Problem constants: B=4, S=1024, DIM=1280, H=16, HD=80
// Inputs fp32 (runtime-probed); OUTPUT FP32.
#define SCALE_F 0.11180339887498949f   // 80^-0.5
#define HDP 96                          // HD padded to multiple of 32 for QK^T

typedef short  short8  __attribute__((ext_vector_type(8)));
typedef short  short4v __attribute__((ext_vector_type(4)));
typedef float  f32x4   __attribute__((ext_vector_type(4)));
typedef __bf16 bf16x8  __attribute__((ext_vector_type(8)));

__device__ __forceinline__ float bf2f(short s) {
  union { unsigned u; float f; } v;
  v.u = ((unsigned)(unsigned short)s) << 16;
  return v.f;
}
__device__ __forceinline__ short f2b(float f) {
  __bf16 h = (__bf16)f;
  return __builtin_bit_cast(short, h);
}
__device__ __forceinline__ bool probe_is_bf16(const unsigned* probe) {
  return (probe[1] & 0xFFFFu) != 0u;
}
__device__ __forceinline__ float load_scalar(const void* p, int i, bool isb) {
  return isb ? bf2f(((const short*)p)[i]) : ((const float*)p)[i];
}

// async global->LDS, 16B per lane. HW LDS placement: wave-uniform base +
// lane*16 (m104/m108); per-lane pointer below coincides with that exactly.
__device__ __forceinline__ void gload_lds16(const short* g, short* l) {
  __builtin_amdgcn_global_load_lds(
      (const __attribute__((address_space(1))) void*)g,
      (__attribute__((address_space(3))) void*)l, 16, 0, 0);
}

template <typename V>
__device__ __forceinline__ auto mfma_try(V a, V b, f32x4 c, int)
    -> decltype(__builtin_amdgcn_mfma_f32_16x16x32_bf16(a, b, c, 0, 0, 0)) {
  return __builtin_amdgcn_mfma_f32_16x16x32_bf16(a, b, c, 0, 0, 0);
}
template <typename V>
__device__ __forceinline__ f32x4 mfma_try(V a, V b, f32x4 c, long) {
  return __builtin_amdgcn_mfma_f32_16x16x32_bf16(
      __builtin_bit_cast(bf16x8, a), __builtin_bit_cast(bf16x8, b), c, 0, 0, 0);
}
__device__ __forceinline__ f32x4 MFMA(short8 a, short8 b, f32x4 c) {
  return mfma_try(a, b, c, 0);
}

// ------------------------------------------------------- canonicalize: x->bf16
__global__ __launch_bounds__(256) void cvt_x_kernel(
    const void* __restrict__ xin, short* __restrict__ xout,
    const unsigned* __restrict__ probe) {
  bool isb = probe_is_bf16(probe);
  size_t i = ((size_t)blockIdx.x * 256 + threadIdx.x) * 8;
  if (isb) {
    *(short8*)&xout[i] = *(const short8*)((const short*)xin + i);
  } else {
    const float* f = (const float*)xin + i;
    float4 a0 = *(const float4*)f;
    float4 a1 = *(const float4*)(f + 4);
    short8 sv;
    sv[0] = f2b(a0.x); sv[1] = f2b(a0.y); sv[2] = f2b(a0.z); sv[3] = f2b(a0.w);
    sv[4] = f2b(a1.x); sv[5] = f2b(a1.y); sv[6] = f2b(a1.z); sv[7] = f2b(a1.w);
    *(short8*)&xout[i] = sv;
  }
}

// ---------------------------------------------------------------- transpose
__global__ __launch_bounds__(256) void transpose_kernel(
    const void* __restrict__ in, short* __restrict__ out, int R, int C,
    const unsigned* __restrict__ probe) {
  bool isb = probe_is_bf16(probe);
  __shared__ float tile[32][33];
  int t = threadIdx.x;
  int bx = blockIdx.x;  // over C
  int by = blockIdx.y;  // over R
  int r = t >> 3, c4 = (t & 7) * 4;
  size_t idx = (size_t)(by * 32 + r) * C + bx * 32 + c4;
  if (isb) {
    short4v v = *(const short4v*)((const short*)in + idx);
    tile[r][c4 + 0] = bf2f(v[0]);
    tile[r][c4 + 1] = bf2f(v[1]);
    tile[r][c4 + 2] = bf2f(v[2]);
    tile[r][c4 + 3] = bf2f(v[3]);
  } else {
    float4 v = *(const float4*)((const float*)in + idx);
    tile[r][c4 + 0] = v.x;
    tile[r][c4 + 1] = v.y;
    tile[r][c4 + 2] = v.z;
    tile[r][c4 + 3] = v.w;
  }
  __syncthreads();
  int rr = t >> 3, k4 = (t & 7) * 4;
  short4v o;
  o[0] = f2b(tile[k4 + 0][rr]);
  o[1] = f2b(tile[k4 + 1][rr]);
  o[2] = f2b(tile[k4 + 2][rr]);
  o[3] = f2b(tile[k4 + 3][rr]);
  *(short4v*)&out[(size_t)(bx * 32 + rr) * R + by * 32 + k4] = o;
}

// ---------------------------------------------------------------- QKV GEMM
// r8 = verified r6 skeleton (256x256, BK=64, 8 waves, 8-phase, T2 swizzle
// with 0 measured conflicts, counted vmcnt at ph3/ph7, 1 barrier/phase)
// + register-hoist of fragments: A-half fragments read ONCE per (S,HA) pair
// (afr reused at ph1/ph3/ph5/ph7), B-halves read ONCE per S-group (bf0/bf1
// reused across QM quadrants). Reads/phase: 12 -> {16,0,8,0} avg 6. All
// barriers / vmcnt / staging ring IDENTICAL to r6; moved reads stay inside
// the same publish epochs (ph3/ph7 vmcnt(4)+barrier), and every buffer's
// last read still completes (lgkmcnt before MFMA) before its overwriting
// stage issues (always >=1 barrier later).
__global__ __launch_bounds__(512, 2) void gemm_qkv_kernel(
    const short* __restrict__ X, const short* __restrict__ Wt,
    const void* __restrict__ bias, const unsigned* __restrict__ probe,
    short* __restrict__ Qw, short* __restrict__ Kw, short* __restrict__ Vt) {
  const int K = 1280;
  __shared__ short Al[2][2][8192];   // [slot][half][128*64]
  __shared__ short Bl[2][2][8192];
  int t = threadIdx.x;
  int bm = blockIdx.x / 15, bn = blockIdx.x % 15;
  int m0 = bm * 256, n0 = bn * 256;
  int w = t >> 6, lane = t & 63;
  int quad = lane >> 4, l16 = lane & 15, l8 = l16 & 7;
  int arow = (w >> 2) * 64 + l16;   // + mt*16 -> A row within half
  int brow = (w & 3) * 32 + l16;    // + nt*16 -> B row within half
  int sr = t >> 3, t8s = t * 8;
  int sjs = (t & 7) ^ (sr & 7);     // pre-swizzled global k-slot (involution)
  int soff0 = ((quad ^ l8) * 8);
  int soff1 = (((4 + quad) ^ l8) * 8);
  f32x4 acc[2][2][4][2] = {};       // [qm][qn][mt][nt], all-static indexing
  short8 afr[4][2];                 // A fragments of current (S,HA)
  short8 bf0[2][2], bf1[2][2];      // B fragments, half0 / half1 of current S

#define STAGE8(PTR, R0, KOFF, LP)                                            \
  {                                                                          \
    const short* g_ = (PTR) + (size_t)((R0) + sr) * 1280 + (KOFF) + sjs * 8; \
    gload_lds16(g_, (LP) + t8s);                                             \
    gload_lds16(g_ + 64 * 1280, (LP) + t8s + 4096);                          \
  }

#define READ_A(S, H)                                                         \
  {                                                                          \
    _Pragma("unroll") for (int mt = 0; mt < 4; mt++) {                       \
      int rp_ = (arow + mt * 16) * 64;                                       \
      afr[mt][0] = *(const short8*)&Al[S][H][rp_ + soff0];                   \
      afr[mt][1] = *(const short8*)&Al[S][H][rp_ + soff1];                   \
    }                                                                        \
  }
#define READ_B(DST, S, H)                                                    \
  {                                                                          \
    _Pragma("unroll") for (int nt = 0; nt < 2; nt++) {                       \
      int rp_ = (brow + nt * 16) * 64;                                       \
      DST[nt][0] = *(const short8*)&Bl[S][H][rp_ + soff0];                   \
      DST[nt][1] = *(const short8*)&Bl[S][H][rp_ + soff1];                   \
    }                                                                        \
  }
// MFMA cluster; WAITI = lgkmcnt count to wait for (counted: trailing reads
// may still be in flight if not needed by THIS cluster).
#define MFMA16(QM, QN, BF, WAITI)                                            \
  {                                                                          \
    asm volatile("s_waitcnt lgkmcnt(" #WAITI ")" ::: "memory");              \
    __builtin_amdgcn_sched_barrier(0);                                       \
    __builtin_amdgcn_s_setprio(1);                                           \
    _Pragma("unroll") for (int mt = 0; mt < 4; mt++)                         \
      _Pragma("unroll") for (int nt = 0; nt < 2; nt++) {                     \
        acc[QM][QN][mt][nt] = MFMA(afr[mt][0], BF[nt][0], acc[QM][QN][mt][nt]); \
        acc[QM][QN][mt][nt] = MFMA(afr[mt][1], BF[nt][1], acc[QM][QN][mt][nt]); \
      }                                                                      \
    __builtin_amdgcn_s_setprio(0);                                           \
  }
#define BAR() __builtin_amdgcn_s_barrier()
#define VW4()                                                                \
  {                                                                          \
    asm volatile("s_waitcnt vmcnt(4)" ::: "memory");                         \
    __builtin_amdgcn_sched_barrier(0);                                       \
  }

  // prologue: tile0 (all 4 halves) + tile1 (A0,B0) = 12 loads/thread
  STAGE8(X,  m0,       0,  &Al[0][0][0]);
  STAGE8(X,  m0 + 128, 0,  &Al[0][1][0]);
  STAGE8(Wt, n0,       0,  &Bl[0][0][0]);
  STAGE8(Wt, n0 + 128, 0,  &Bl[0][1][0]);
  STAGE8(X,  m0,       64, &Al[1][0][0]);
  STAGE8(Wt, n0,       64, &Bl[1][0][0]);
  VW4();   // tile0's 8 loads landed
  BAR();

  for (int i = 0; i < 10; i++) {
    int k1 = (2 * i + 1) * 64;                       // <= 1216, always valid
    int k2 = (2 * i + 2) * 64; if (k2 >= K) k2 = 0;  // dummy (unread) on tail
    int k3 = (2 * i + 3) * 64; if (k3 >= K) k3 = 0;
    // ---- S=0 group ----
    READ_A(0, 0); READ_B(bf0, 0, 0); READ_B(bf1, 0, 1);   // 16 reads
    STAGE8(X,  m0 + 128, k1, &Al[1][1][0]);
    MFMA16(0, 0, bf0, 4);   // bf1's 4 reads land under the MFMAs
    BAR();                                                        // ph0
    STAGE8(Wt, n0 + 128, k1, &Bl[1][1][0]);
    MFMA16(0, 1, bf1, 0);
    BAR();                                                        // ph1
    READ_A(0, 1);                                          // 8 reads
    STAGE8(X,  m0,       k2, &Al[0][0][0]);
    MFMA16(1, 0, bf0, 0);
    BAR();                                                        // ph2
    STAGE8(Wt, n0,       k2, &Bl[0][0][0]);
    MFMA16(1, 1, bf1, 0);
    VW4();
    BAR();                                                        // ph3
    // ---- S=1 group ----
    READ_A(1, 0); READ_B(bf0, 1, 0); READ_B(bf1, 1, 1);
    STAGE8(X,  m0 + 128, k2, &Al[0][1][0]);
    MFMA16(0, 0, bf0, 4);
    BAR();                                                        // ph4
    STAGE8(Wt, n0 + 128, k2, &Bl[0][1][0]);
    MFMA16(0, 1, bf1, 0);
    BAR();                                                        // ph5
    READ_A(1, 1);
    STAGE8(X,  m0,       k3, &Al[1][0][0]);
    MFMA16(1, 0, bf0, 0);
    BAR();                                                        // ph6
    STAGE8(Wt, n0,       k3, &Bl[1][0][0]);
    MFMA16(1, 1, bf1, 0);
    VW4();
    BAR();                                                        // ph7
  }
  asm volatile("s_waitcnt vmcnt(0)" ::: "memory");   // drain dummy stages
  __builtin_amdgcn_sched_barrier(0);

  bool isb = probe_is_bf16(probe);
  float bv[2][2];
#pragma unroll
  for (int qn = 0; qn < 2; qn++)
#pragma unroll
    for (int nt = 0; nt < 2; nt++)
      bv[qn][nt] =
          load_scalar(bias, n0 + qn * 128 + (w & 3) * 32 + nt * 16 + l16, isb);
#pragma unroll
  for (int qm = 0; qm < 2; qm++)
#pragma unroll
    for (int mt = 0; mt < 4; mt++) {
      int mbase = m0 + qm * 128 + (w >> 2) * 64 + mt * 16 + quad * 4;
      int b = mbase >> 10, sbase = mbase & 1023;
#pragma unroll
      for (int qn = 0; qn < 2; qn++)
#pragma unroll
        for (int nt = 0; nt < 2; nt++) {
          int n = n0 + qn * 128 + (w & 3) * 32 + nt * 16 + l16;
          int which = n / 1280;
          int rmod = n - which * 1280;
          int h = rmod / 80;
          int d = rmod - h * 80;
          int bh = b * 16 + h;
          if (which == 2) {
            short4v vv;
#pragma unroll
            for (int reg = 0; reg < 4; reg++)
              vv[reg] = f2b(acc[qm][qn][mt][nt][reg] + bv[qn][nt]);
            *(short4v*)&Vt[((size_t)bh * 80 + d) * 1024 + sbase] = vv;
          } else {
            short* dst = (which == 0 ? Qw : Kw);
#pragma unroll
            for (int reg = 0; reg < 4; reg++)
              dst[((size_t)bh * 1024 + sbase + reg) * HDP + d] =
                  f2b(acc[qm][qn][mt][nt][reg] + bv[qn][nt]);
          }
        }
    }
#undef STAGE8
#undef READ_A
#undef READ_B
#undef MFMA16
#undef BAR
#undef VW4
}

// ---------------------------------------------------------------- RoPE
__global__ __launch_bounds__(256) void rope_kernel(
    short* __restrict__ Qw, short* __restrict__ Kw,
    const void* __restrict__ cosb, const void* __restrict__ sinb,
    const unsigned* __restrict__ probe) {
  bool isb = probe_is_bf16(probe);
  int t = threadIdx.x;
  int w = t >> 6, lane = t & 63;
  int job = blockIdx.x * 4 + w;   // 64*1024*2 jobs
  int which = job & 1;
  int row = job >> 1;             // bh*1024 + s
  int s = row & 1023;
  short* ptr = (which ? Kw : Qw) + (size_t)row * HDP;
  float scale = which ? 1.0f : SCALE_F;
  if (lane < 40) {
    float p0 = bf2f(ptr[lane]);
    float p1 = bf2f(ptr[lane + 40]);
    float c0 = load_scalar(cosb, s * 80 + lane, isb);
    float s0 = load_scalar(sinb, s * 80 + lane, isb);
    float c1 = load_scalar(cosb, s * 80 + lane + 40, isb);
    float s1 = load_scalar(sinb, s * 80 + lane + 40, isb);
    ptr[lane] = f2b((p0 * c0 - p1 * s0) * scale);
    ptr[lane + 40] = f2b((p1 * c1 + p0 * s1) * scale);
  } else if (lane < 56) {
    ptr[40 + lane] = 0;  // d = 80..95
  }
}

// ---------------------------------------------------------------- attention
// 8 waves / 128 q-rows per block; double-buffered K/V LDS, one barrier per
// chunk (verified r6).
__global__ __launch_bounds__(512, 4) void attn_kernel(
    const short* __restrict__ Qw, const short* __restrict__ Kw,
    const short* __restrict__ Vt, short* __restrict__ out) {
  __shared__ short Klds[2][64 * 104];
  __shared__ short Vlds[2][80 * 72];
  __shared__ short Ps[8][16 * 72];
  int t = threadIdx.x;
  int w = t >> 6, lane = t & 63;
  int quad = lane >> 4, l16 = lane & 15;
  int bh = blockIdx.x & 63;        // XCD swizzle: same bh -> same XCD
  int qt = blockIdx.x >> 6;        // 0..3
  int q0 = qt * 128;
  const short* Kb = Kw + (size_t)bh * 1024 * HDP;
  const short* Vb = Vt + (size_t)bh * 80 * 1024;

  // Q fragments (pre-scaled by SCALE_F in rope), one-time global read
  short8 aq[3];
  {
    const short* qrow = Qw + ((size_t)bh * 1024 + q0 + w * 16 + l16) * HDP;
#pragma unroll
    for (int ks = 0; ks < 3; ks++)
      aq[ks] = *(const short8*)&qrow[ks * 32 + quad * 8];
  }

  // staging with 512 threads: K 64x96 = 768 slots; V 80x64 = 640 slots
  short8 kreg[2], vreg[2];
#define PREFETCH(c)                                                        \
  {                                                                        \
    {                                                                      \
      int row = t / 12, col = (t % 12) * 8;                                \
      kreg[0] = *(const short8*)&Kb[(size_t)((c) + row) * HDP + col];      \
    }                                                                      \
    if (t < 256) {                                                         \
      int idx = 512 + t;                                                   \
      int row = idx / 12, col = (idx % 12) * 8;                            \
      kreg[1] = *(const short8*)&Kb[(size_t)((c) + row) * HDP + col];      \
    }                                                                      \
    {                                                                      \
      int d = t >> 3, s0 = (t & 7) * 8;                                    \
      vreg[0] = *(const short8*)&Vb[(size_t)d * 1024 + (c) + s0];          \
    }                                                                      \
    if (t < 128) {                                                         \
      int idx = 512 + t;                                                   \
      int d = idx >> 3, s0 = (idx & 7) * 8;                                \
      vreg[1] = *(const short8*)&Vb[(size_t)d * 1024 + (c) + s0];          \
    }                                                                      \
  }
#define STORE_LDS(P)                                                       \
  {                                                                        \
    {                                                                      \
      int row = t / 12, col = (t % 12) * 8;                                \
      *(short8*)&Klds[P][row * 104 + col] = kreg[0];                       \
    }                                                                      \
    if (t < 256) {                                                         \
      int idx = 512 + t;                                                   \
      int row = idx / 12, col = (idx % 12) * 8;                            \
      *(short8*)&Klds[P][row * 104 + col] = kreg[1];                       \
    }                                                                      \
    {                                                                      \
      int d = t >> 3, s0 = (t & 7) * 8;                                    \
      *(short8*)&Vlds[P][d * 72 + s0] = vreg[0];                           \
    }                                                                      \
    if (t < 128) {                                                         \
      int idx = 512 + t;                                                   \
      int d = idx >> 3, s0 = (idx & 7) * 8;                                \
      *(short8*)&Vlds[P][d * 72 + s0] = vreg[1];                           \
    }                                                                      \
  }

  PREFETCH(0);
  STORE_LDS(0);
  __syncthreads();

  f32x4 ofr[5] = {};
  float lsum[4] = {0.f, 0.f, 0.f, 0.f};
  short* Pw = &Ps[w][0];

  int p = 0;
  for (int c = 0; c < 1024; c += 64, p ^= 1) {
    if (c + 64 < 1024) PREFETCH(c + 64);   // global loads fly under compute
    const short* Kl = &Klds[p][0];
    const short* Vl = &Vlds[p][0];
    // QK^T chunk from LDS: S(16x64) per wave
    f32x4 sf[4] = {};
#pragma unroll
    for (int nt = 0; nt < 4; nt++) {
      short8 bk0 = *(const short8*)&Kl[(nt * 16 + l16) * 104 + 0 * 32 + quad * 8];
      short8 bk1 = *(const short8*)&Kl[(nt * 16 + l16) * 104 + 1 * 32 + quad * 8];
      short8 bk2 = *(const short8*)&Kl[(nt * 16 + l16) * 104 + 2 * 32 + quad * 8];
      sf[nt] = MFMA(aq[0], bk0, sf[nt]);
      sf[nt] = MFMA(aq[1], bk1, sf[nt]);
      sf[nt] = MFMA(aq[2], bk2, sf[nt]);
    }
    // unsafe softmax: p = exp(min(s,30)); per-lane partial row sums only
#pragma unroll
    for (int r = 0; r < 4; r++) {
      float p0 = __expf(fminf(sf[0][r], 30.f));
      float p1 = __expf(fminf(sf[1][r], 30.f));
      float p2 = __expf(fminf(sf[2][r], 30.f));
      float p3 = __expf(fminf(sf[3][r], 30.f));
      sf[0][r] = p0; sf[1][r] = p1; sf[2][r] = p2; sf[3][r] = p3;
      lsum[r] += (p0 + p1) + (p2 + p3);
    }
    // P -> per-wave LDS (C-layout -> A-layout); DS in-order within wave
#pragma unroll
    for (int nt = 0; nt < 4; nt++)
#pragma unroll
      for (int r = 0; r < 4; r++)
        Pw[(quad * 4 + r) * 72 + nt * 16 + l16] = f2b(sf[nt][r]);
    __threadfence_block();
    short8 ap[2];
#pragma unroll
    for (int ks = 0; ks < 2; ks++)
      ap[ks] = *(const short8*)&Pw[l16 * 72 + ks * 32 + quad * 8];
    // PV from LDS V tile
#pragma unroll
    for (int nt = 0; nt < 5; nt++) {
      short8 bv0 = *(const short8*)&Vl[(nt * 16 + l16) * 72 + 0 * 32 + quad * 8];
      short8 bv1 = *(const short8*)&Vl[(nt * 16 + l16) * 72 + 1 * 32 + quad * 8];
      ofr[nt] = MFMA(ap[0], bv0, ofr[nt]);
      ofr[nt] = MFMA(ap[1], bv1, ofr[nt]);
    }
    if (c + 64 < 1024) {
      STORE_LDS(p ^ 1);       // idle buffer; readers of it passed last barrier
      __syncthreads();        // publish + close this iter's reads of buf p
    }
  }
  // single end-of-kernel reduction: row sums across the 16-lane groups
#pragma unroll
  for (int off = 1; off < 16; off <<= 1)
#pragma unroll
    for (int r = 0; r < 4; r++) lsum[r] += __shfl_xor(lsum[r], off);
  float inv[4];
#pragma unroll
  for (int r = 0; r < 4; r++) inv[r] = 1.f / lsum[r];
  int b = bh >> 4, h = bh & 15;
#pragma unroll
  for (int nt = 0; nt < 5; nt++) {
    int d = nt * 16 + l16;
#pragma unroll
    for (int r = 0; r < 4; r++) {
      int s = q0 + w * 16 + quad * 4 + r;
      out[((size_t)(b * 1024 + s)) * 1280 + h * 80 + d] = f2b(ofr[nt][r] * inv[r]);
    }
  }
}

// ---------------------------------------------------------------- proj GEMM
__global__ __launch_bounds__(256) void gemm_proj_kernel(
    const short* __restrict__ A, const short* __restrict__ Wt,
    const void* __restrict__ bias, const unsigned* __restrict__ probe,
    float* __restrict__ out) {
  const int K = 1280;
  __shared__ short As[2][128 * 32];
  __shared__ short Bs[2][128 * 32];
  int t = threadIdx.x;
  int bm = blockIdx.x / 10;
  int bn = blockIdx.x % 10;
  int m0 = bm * 128, n0 = bn * 128;
  int w = t >> 6, lane = t & 63;
  int wm = w & 1, wn = w >> 1;
  int quad = lane >> 4, l16 = lane & 15;
  int row = t >> 2, ch = (t & 3) * 8, row2 = row + 64;
  int t8 = t * 8;
  const short* Ar  = A  + (size_t)(m0 + row)  * K + ch;
  const short* Ar2 = A  + (size_t)(m0 + row2) * K + ch;
  const short* Wr  = Wt + (size_t)(n0 + row)  * K + ch;
  const short* Wr2 = Wt + (size_t)(n0 + row2) * K + ch;
  f32x4 acc[4][4] = {};
  gload_lds16(Ar,  &As[0][t8]);
  gload_lds16(Ar2, &As[0][t8 + 2048]);
  gload_lds16(Wr,  &Bs[0][t8]);
  gload_lds16(Wr2, &Bs[0][t8 + 2048]);
  __syncthreads();
  int p = 0;
#define PROJ_COMPUTE(pp)                                                      \
  {                                                                           \
    short8 af[4], bfr[4];                                                     \
    _Pragma("unroll") for (int mt = 0; mt < 4; mt++)                          \
        af[mt] = *(const short8*)&As[pp][(wm * 64 + mt * 16 + l16) * 32 + quad * 8]; \
    _Pragma("unroll") for (int nt = 0; nt < 4; nt++)                          \
        bfr[nt] = *(const short8*)&Bs[pp][(wn * 64 + nt * 16 + l16) * 32 + quad * 8]; \
    _Pragma("unroll") for (int mt = 0; mt < 4; mt++)                          \
        _Pragma("unroll") for (int nt = 0; nt < 4; nt++)                      \
            acc[mt][nt] = MFMA(af[mt], bfr[nt], acc[mt][nt]);                 \
  }
  for (int k0 = 32; k0 < K; k0 += 32, p ^= 1) {
    gload_lds16(Ar + k0,  &As[p ^ 1][t8]);
    gload_lds16(Ar2 + k0, &As[p ^ 1][t8 + 2048]);
    gload_lds16(Wr + k0,  &Bs[p ^ 1][t8]);
    gload_lds16(Wr2 + k0, &Bs[p ^ 1][t8 + 2048]);
    PROJ_COMPUTE(p);
    __syncthreads();
  }
  PROJ_COMPUTE(p);
  bool isb = probe_is_bf16(probe);
  float bv[4];
#pragma unroll
  for (int nt = 0; nt < 4; nt++)
    bv[nt] = load_scalar(bias, n0 + wn * 64 + nt * 16 + l16, isb);
#pragma unroll
  for (int mt = 0; mt < 4; mt++) {
#pragma unroll
    for (int nt = 0; nt < 4; nt++) {
      int n = n0 + wn * 64 + nt * 16 + l16;
#pragma unroll
      for (int reg = 0; reg < 4; reg++) {
        int m = m0 + wm * 64 + mt * 16 + quad * 4 + reg;
        out[(size_t)m * 1280 + n] = acc[mt][nt][reg] + bv[nt];  // FP32 store
      }
    }
  }
}

extern "C" void kernel_launch(void* const* d_in, const int* in_sizes, int n_in,
                              void* d_out, int out_size, void* d_ws, size_t ws_size,
                              hipStream_t stream) {
  const void* x        = d_in[0];
  const void* rope_cos = d_in[1];
  const void* rope_sin = d_in[2];
  const void* Wqkv     = d_in[3];
  const void* bqkv     = d_in[4];
  const void* Wproj    = d_in[5];
  const void* bproj    = d_in[6];
  const unsigned* probe = (const unsigned*)rope_cos;
  char* ws = (char*)d_ws;
  short* Wt1 = (short*)(ws + 0);          // 1280*3840*2 = 9,830,400
  short* Wt2 = (short*)(ws + 9830400);    // 1280*1280*2 = 3,276,800
  short* Qw  = (short*)(ws + 13107200);   // 64*1024*96*2 = 12,582,912
  short* Kw  = (short*)(ws + 25690112);   // 12,582,912
  short* Vt  = (short*)(ws + 38273024);   // 64*1024*80*2 = 10,485,760
  short* Xb  = (short*)(ws + 48758784);   // 4096*1280*2 = 10,485,760
  short* At  = (short*)(ws + 48758784);   // aliases Xb (disjoint lifetimes)

  cvt_x_kernel<<<2560, 256, 0, stream>>>(x, Xb, probe);
  transpose_kernel<<<dim3(3840 / 32, 1280 / 32), 256, 0, stream>>>(Wqkv, Wt1, 1280, 3840, probe);
  transpose_kernel<<<dim3(1280 / 32, 1280 / 32), 256, 0, stream>>>(Wproj, Wt2, 1280, 1280, probe);
  gemm_qkv_kernel<<<240, 512, 0, stream>>>(Xb, Wt1, bqkv, probe, Qw, Kw, Vt);
  rope_kernel<<<32768, 256, 0, stream>>>(Qw, Kw, rope_cos, rope_sin, probe);
  attn_kernel<<<512, 512, 0, stream>>>(Qw, Kw, Vt, At);
  gemm_proj_kernel<<<32 * 10, 256, 0, stream>>>(At, Wt2, bproj, probe, (float*)d_out);
}

// Round 9
// 236.918 us; speedup vs baseline: 1.0712x; 1.0309x over previous
//
#include <hip/hip_runtime.h>
#include <math.h>

// Problem constants: B=4, S=1024, DIM=1280, H=16, HD=80
// Inputs fp32 (runtime-probed); OUTPUT FP32.
#define SCALE_F 0.11180339887498949f   // 80^-0.5
#define HDP 96                          // HD padded to multiple of 32 for QK^T

typedef short  short8  __attribute__((ext_vector_type(8)));
typedef short  short4v __attribute__((ext_vector_type(4)));
typedef float  f32x4   __attribute__((ext_vector_type(4)));
typedef __bf16 bf16x8  __attribute__((ext_vector_type(8)));
typedef __bf16 bf16x4  __attribute__((ext_vector_type(4)));

__device__ __forceinline__ float bf2f(short s) {
  union { unsigned u; float f; } v;
  v.u = ((unsigned)(unsigned short)s) << 16;
  return v.f;
}
__device__ __forceinline__ short f2b(float f) {
  __bf16 h = (__bf16)f;
  return __builtin_bit_cast(short, h);
}
__device__ __forceinline__ bool probe_is_bf16(const unsigned* probe) {
  return (probe[1] & 0xFFFFu) != 0u;
}
__device__ __forceinline__ float load_scalar(const void* p, int i, bool isb) {
  return isb ? bf2f(((const short*)p)[i]) : ((const float*)p)[i];
}

// async global->LDS, 16B per lane. HW LDS placement: wave-uniform base +
// lane*16 (m104/m108); per-lane pointer below coincides with that exactly.
__device__ __forceinline__ void gload_lds16(const short* g, short* l) {
  __builtin_amdgcn_global_load_lds(
      (const __attribute__((address_space(1))) void*)g,
      (__attribute__((address_space(3))) void*)l, 16, 0, 0);
}

template <typename V>
__device__ __forceinline__ auto mfma_try(V a, V b, f32x4 c, int)
    -> decltype(__builtin_amdgcn_mfma_f32_16x16x32_bf16(a, b, c, 0, 0, 0)) {
  return __builtin_amdgcn_mfma_f32_16x16x32_bf16(a, b, c, 0, 0, 0);
}
template <typename V>
__device__ __forceinline__ f32x4 mfma_try(V a, V b, f32x4 c, long) {
  return __builtin_amdgcn_mfma_f32_16x16x32_bf16(
      __builtin_bit_cast(bf16x8, a), __builtin_bit_cast(bf16x8, b), c, 0, 0, 0);
}
__device__ __forceinline__ f32x4 MFMA(short8 a, short8 b, f32x4 c) {
  return mfma_try(a, b, c, 0);
}

// 16x16x16 bf16 MFMA (k=16): A/B = 4 bf16 (2 VGPRs), C/D = f32x4.
// Builtin name varies across ROCm; 3-way guarded.
#if __has_builtin(__builtin_amdgcn_mfma_f32_16x16x16bf16_1k)
template <typename V>
__device__ __forceinline__ auto mfma16_try(V a, V b, f32x4 c, int)
    -> decltype(__builtin_amdgcn_mfma_f32_16x16x16bf16_1k(a, b, c, 0, 0, 0)) {
  return __builtin_amdgcn_mfma_f32_16x16x16bf16_1k(a, b, c, 0, 0, 0);
}
template <typename V>
__device__ __forceinline__ f32x4 mfma16_try(V a, V b, f32x4 c, long) {
  return __builtin_amdgcn_mfma_f32_16x16x16bf16_1k(
      __builtin_bit_cast(bf16x4, a), __builtin_bit_cast(bf16x4, b), c, 0, 0, 0);
}
__device__ __forceinline__ f32x4 MFMA16(short4v a, short4v b, f32x4 c) {
  return mfma16_try(a, b, c, 0);
}
#elif __has_builtin(__builtin_amdgcn_mfma_f32_16x16x16_bf16)
template <typename V>
__device__ __forceinline__ auto mfma16_try(V a, V b, f32x4 c, int)
    -> decltype(__builtin_amdgcn_mfma_f32_16x16x16_bf16(a, b, c, 0, 0, 0)) {
  return __builtin_amdgcn_mfma_f32_16x16x16_bf16(a, b, c, 0, 0, 0);
}
template <typename V>
__device__ __forceinline__ f32x4 mfma16_try(V a, V b, f32x4 c, long) {
  return __builtin_amdgcn_mfma_f32_16x16x16_bf16(
      __builtin_bit_cast(bf16x4, a), __builtin_bit_cast(bf16x4, b), c, 0, 0, 0);
}
__device__ __forceinline__ f32x4 MFMA16(short4v a, short4v b, f32x4 c) {
  return mfma16_try(a, b, c, 0);
}
#else
__device__ __forceinline__ f32x4 MFMA16(short4v a, short4v b, f32x4 c) {
  asm volatile("v_mfma_f32_16x16x16_bf16 %0, %1, %2, %0"
               : "+v"(c) : "v"(a), "v"(b));
  return c;
}
#endif

// ------------------------------------------------------- canonicalize: x->bf16
__global__ __launch_bounds__(256) void cvt_x_kernel(
    const void* __restrict__ xin, short* __restrict__ xout,
    const unsigned* __restrict__ probe) {
  bool isb = probe_is_bf16(probe);
  size_t i = ((size_t)blockIdx.x * 256 + threadIdx.x) * 8;
  if (isb) {
    *(short8*)&xout[i] = *(const short8*)((const short*)xin + i);
  } else {
    const float* f = (const float*)xin + i;
    float4 a0 = *(const float4*)f;
    float4 a1 = *(const float4*)(f + 4);
    short8 sv;
    sv[0] = f2b(a0.x); sv[1] = f2b(a0.y); sv[2] = f2b(a0.z); sv[3] = f2b(a0.w);
    sv[4] = f2b(a1.x); sv[5] = f2b(a1.y); sv[6] = f2b(a1.z); sv[7] = f2b(a1.w);
    *(short8*)&xout[i] = sv;
  }
}

// ---------------------------------------------------------------- transpose
__global__ __launch_bounds__(256) void transpose_kernel(
    const void* __restrict__ in, short* __restrict__ out, int R, int C,
    const unsigned* __restrict__ probe) {
  bool isb = probe_is_bf16(probe);
  __shared__ float tile[32][33];
  int t = threadIdx.x;
  int bx = blockIdx.x;  // over C
  int by = blockIdx.y;  // over R
  int r = t >> 3, c4 = (t & 7) * 4;
  size_t idx = (size_t)(by * 32 + r) * C + bx * 32 + c4;
  if (isb) {
    short4v v = *(const short4v*)((const short*)in + idx);
    tile[r][c4 + 0] = bf2f(v[0]);
    tile[r][c4 + 1] = bf2f(v[1]);
    tile[r][c4 + 2] = bf2f(v[2]);
    tile[r][c4 + 3] = bf2f(v[3]);
  } else {
    float4 v = *(const float4*)((const float*)in + idx);
    tile[r][c4 + 0] = v.x;
    tile[r][c4 + 1] = v.y;
    tile[r][c4 + 2] = v.z;
    tile[r][c4 + 3] = v.w;
  }
  __syncthreads();
  int rr = t >> 3, k4 = (t & 7) * 4;
  short4v o;
  o[0] = f2b(tile[k4 + 0][rr]);
  o[1] = f2b(tile[k4 + 1][rr]);
  o[2] = f2b(tile[k4 + 2][rr]);
  o[3] = f2b(tile[k4 + 3][rr]);
  *(short4v*)&out[(size_t)(bx * 32 + rr) * R + by * 32 + k4] = o;
}

// ---------------------------------------------------------------- QKV GEMM
// r8 structure (verified): 256x256, BK=64, 8 waves, 8-phase, T2 swizzle
// (0 conflicts), counted vmcnt at ph3/ph7, 1 barrier/phase, register-hoisted
// A/B fragments.
__global__ __launch_bounds__(512, 2) void gemm_qkv_kernel(
    const short* __restrict__ X, const short* __restrict__ Wt,
    const void* __restrict__ bias, const unsigned* __restrict__ probe,
    short* __restrict__ Qw, short* __restrict__ Kw, short* __restrict__ Vt) {
  const int K = 1280;
  __shared__ short Al[2][2][8192];   // [slot][half][128*64]
  __shared__ short Bl[2][2][8192];
  int t = threadIdx.x;
  int bm = blockIdx.x / 15, bn = blockIdx.x % 15;
  int m0 = bm * 256, n0 = bn * 256;
  int w = t >> 6, lane = t & 63;
  int quad = lane >> 4, l16 = lane & 15, l8 = l16 & 7;
  int arow = (w >> 2) * 64 + l16;   // + mt*16 -> A row within half
  int brow = (w & 3) * 32 + l16;    // + nt*16 -> B row within half
  int sr = t >> 3, t8s = t * 8;
  int sjs = (t & 7) ^ (sr & 7);     // pre-swizzled global k-slot (involution)
  int soff0 = ((quad ^ l8) * 8);
  int soff1 = (((4 + quad) ^ l8) * 8);
  f32x4 acc[2][2][4][2] = {};       // [qm][qn][mt][nt], all-static indexing
  short8 afr[4][2];                 // A fragments of current (S,HA)
  short8 bf0[2][2], bf1[2][2];      // B fragments, half0 / half1 of current S

#define STAGE8(PTR, R0, KOFF, LP)                                            \
  {                                                                          \
    const short* g_ = (PTR) + (size_t)((R0) + sr) * 1280 + (KOFF) + sjs * 8; \
    gload_lds16(g_, (LP) + t8s);                                             \
    gload_lds16(g_ + 64 * 1280, (LP) + t8s + 4096);                          \
  }

#define READ_A(S, H)                                                         \
  {                                                                          \
    _Pragma("unroll") for (int mt = 0; mt < 4; mt++) {                       \
      int rp_ = (arow + mt * 16) * 64;                                       \
      afr[mt][0] = *(const short8*)&Al[S][H][rp_ + soff0];                   \
      afr[mt][1] = *(const short8*)&Al[S][H][rp_ + soff1];                   \
    }                                                                        \
  }
#define READ_B(DST, S, H)                                                    \
  {                                                                          \
    _Pragma("unroll") for (int nt = 0; nt < 2; nt++) {                       \
      int rp_ = (brow + nt * 16) * 64;                                       \
      DST[nt][0] = *(const short8*)&Bl[S][H][rp_ + soff0];                   \
      DST[nt][1] = *(const short8*)&Bl[S][H][rp_ + soff1];                   \
    }                                                                        \
  }
#define MFMA16C(QM, QN, BF, WAITI)                                           \
  {                                                                          \
    asm volatile("s_waitcnt lgkmcnt(" #WAITI ")" ::: "memory");              \
    __builtin_amdgcn_sched_barrier(0);                                       \
    __builtin_amdgcn_s_setprio(1);                                           \
    _Pragma("unroll") for (int mt = 0; mt < 4; mt++)                         \
      _Pragma("unroll") for (int nt = 0; nt < 2; nt++) {                     \
        acc[QM][QN][mt][nt] = MFMA(afr[mt][0], BF[nt][0], acc[QM][QN][mt][nt]); \
        acc[QM][QN][mt][nt] = MFMA(afr[mt][1], BF[nt][1], acc[QM][QN][mt][nt]); \
      }                                                                      \
    __builtin_amdgcn_s_setprio(0);                                           \
  }
#define BAR() __builtin_amdgcn_s_barrier()
#define VW4()                                                                \
  {                                                                          \
    asm volatile("s_waitcnt vmcnt(4)" ::: "memory");                         \
    __builtin_amdgcn_sched_barrier(0);                                       \
  }

  // prologue: tile0 (all 4 halves) + tile1 (A0,B0) = 12 loads/thread
  STAGE8(X,  m0,       0,  &Al[0][0][0]);
  STAGE8(X,  m0 + 128, 0,  &Al[0][1][0]);
  STAGE8(Wt, n0,       0,  &Bl[0][0][0]);
  STAGE8(Wt, n0 + 128, 0,  &Bl[0][1][0]);
  STAGE8(X,  m0,       64, &Al[1][0][0]);
  STAGE8(Wt, n0,       64, &Bl[1][0][0]);
  VW4();   // tile0's 8 loads landed
  BAR();

  for (int i = 0; i < 10; i++) {
    int k1 = (2 * i + 1) * 64;                       // <= 1216, always valid
    int k2 = (2 * i + 2) * 64; if (k2 >= K) k2 = 0;  // dummy (unread) on tail
    int k3 = (2 * i + 3) * 64; if (k3 >= K) k3 = 0;
    // ---- S=0 group ----
    READ_A(0, 0); READ_B(bf0, 0, 0); READ_B(bf1, 0, 1);   // 16 reads
    STAGE8(X,  m0 + 128, k1, &Al[1][1][0]);
    MFMA16C(0, 0, bf0, 4);   // bf1's 4 reads land under the MFMAs
    BAR();                                                        // ph0
    STAGE8(Wt, n0 + 128, k1, &Bl[1][1][0]);
    MFMA16C(0, 1, bf1, 0);
    BAR();                                                        // ph1
    READ_A(0, 1);                                          // 8 reads
    STAGE8(X,  m0,       k2, &Al[0][0][0]);
    MFMA16C(1, 0, bf0, 0);
    BAR();                                                        // ph2
    STAGE8(Wt, n0,       k2, &Bl[0][0][0]);
    MFMA16C(1, 1, bf1, 0);
    VW4();
    BAR();                                                        // ph3
    // ---- S=1 group ----
    READ_A(1, 0); READ_B(bf0, 1, 0); READ_B(bf1, 1, 1);
    STAGE8(X,  m0 + 128, k2, &Al[0][1][0]);
    MFMA16C(0, 0, bf0, 4);
    BAR();                                                        // ph4
    STAGE8(Wt, n0 + 128, k2, &Bl[0][1][0]);
    MFMA16C(0, 1, bf1, 0);
    BAR();                                                        // ph5
    READ_A(1, 1);
    STAGE8(X,  m0,       k3, &Al[1][0][0]);
    MFMA16C(1, 0, bf0, 0);
    BAR();                                                        // ph6
    STAGE8(Wt, n0,       k3, &Bl[1][0][0]);
    MFMA16C(1, 1, bf1, 0);
    VW4();
    BAR();                                                        // ph7
  }
  asm volatile("s_waitcnt vmcnt(0)" ::: "memory");   // drain dummy stages
  __builtin_amdgcn_sched_barrier(0);

  bool isb = probe_is_bf16(probe);
  float bv[2][2];
#pragma unroll
  for (int qn = 0; qn < 2; qn++)
#pragma unroll
    for (int nt = 0; nt < 2; nt++)
      bv[qn][nt] =
          load_scalar(bias, n0 + qn * 128 + (w & 3) * 32 + nt * 16 + l16, isb);
#pragma unroll
  for (int qm = 0; qm < 2; qm++)
#pragma unroll
    for (int mt = 0; mt < 4; mt++) {
      int mbase = m0 + qm * 128 + (w >> 2) * 64 + mt * 16 + quad * 4;
      int b = mbase >> 10, sbase = mbase & 1023;
#pragma unroll
      for (int qn = 0; qn < 2; qn++)
#pragma unroll
        for (int nt = 0; nt < 2; nt++) {
          int n = n0 + qn * 128 + (w & 3) * 32 + nt * 16 + l16;
          int which = n / 1280;
          int rmod = n - which * 1280;
          int h = rmod / 80;
          int d = rmod - h * 80;
          int bh = b * 16 + h;
          if (which == 2) {
            short4v vv;
#pragma unroll
            for (int reg = 0; reg < 4; reg++)
              vv[reg] = f2b(acc[qm][qn][mt][nt][reg] + bv[qn][nt]);
            *(short4v*)&Vt[((size_t)bh * 80 + d) * 1024 + sbase] = vv;
          } else {
            short* dst = (which == 0 ? Qw : Kw);
#pragma unroll
            for (int reg = 0; reg < 4; reg++)
              dst[((size_t)bh * 1024 + sbase + reg) * HDP + d] =
                  f2b(acc[qm][qn][mt][nt][reg] + bv[qn][nt]);
          }
        }
    }
#undef STAGE8
#undef READ_A
#undef READ_B
#undef MFMA16C
#undef BAR
#undef VW4
}

// ---------------------------------------------------------------- RoPE
__global__ __launch_bounds__(256) void rope_kernel(
    short* __restrict__ Qw, short* __restrict__ Kw,
    const void* __restrict__ cosb, const void* __restrict__ sinb,
    const unsigned* __restrict__ probe) {
  bool isb = probe_is_bf16(probe);
  int t = threadIdx.x;
  int w = t >> 6, lane = t & 63;
  int job = blockIdx.x * 4 + w;   // 64*1024*2 jobs
  int which = job & 1;
  int row = job >> 1;             // bh*1024 + s
  int s = row & 1023;
  short* ptr = (which ? Kw : Qw) + (size_t)row * HDP;
  float scale = which ? 1.0f : SCALE_F;
  if (lane < 40) {
    float p0 = bf2f(ptr[lane]);
    float p1 = bf2f(ptr[lane + 40]);
    float c0 = load_scalar(cosb, s * 80 + lane, isb);
    float s0 = load_scalar(sinb, s * 80 + lane, isb);
    float c1 = load_scalar(cosb, s * 80 + lane + 40, isb);
    float s1 = load_scalar(sinb, s * 80 + lane + 40, isb);
    ptr[lane] = f2b((p0 * c0 - p1 * s0) * scale);
    ptr[lane + 40] = f2b((p1 * c1 + p0 * s1) * scale);
  } else if (lane < 56) {
    ptr[40 + lane] = 0;  // d = 80..95
  }
}

// ---------------------------------------------------------------- attention
// r9: swapped QK^T (T12 analog) -> P stays in registers, no P LDS roundtrip.
// MFMA(K,Q) gives S^T: lane l16 = q, quad*4+r = kv. After exp, the packed
// bf16x4 per kv-block IS the 16x16x16 B-operand (col=q=l16, k=quad*4+j) for
// O^T = V^T*P: A = V rows d (Vlds b64 read), C: lane l16 = q, quad*4+reg = d.
// Row-sum is one scalar/lane + 2 shuffles; output packs 4 consecutive d.
// Double-buffered K/V + single barrier/iter kept from r6.
__global__ __launch_bounds__(512, 4) void attn_kernel(
    const short* __restrict__ Qw, const short* __restrict__ Kw,
    const short* __restrict__ Vt, short* __restrict__ out) {
  __shared__ short Klds[2][64 * 104];
  __shared__ short Vlds[2][80 * 72];
  int t = threadIdx.x;
  int w = t >> 6, lane = t & 63;
  int quad = lane >> 4, l16 = lane & 15;
  int bh = blockIdx.x & 63;        // XCD swizzle: same bh -> same XCD
  int qt = blockIdx.x >> 6;        // 0..7
  int q0 = qt * 128;
  const short* Kb = Kw + (size_t)bh * 1024 * HDP;
  const short* Vb = Vt + (size_t)bh * 80 * 1024;

  // Q fragments (pre-scaled by SCALE_F in rope); B-operand of swapped QK^T
  short8 aq[3];
  {
    const short* qrow = Qw + ((size_t)bh * 1024 + q0 + w * 16 + l16) * HDP;
#pragma unroll
    for (int ks = 0; ks < 3; ks++)
      aq[ks] = *(const short8*)&qrow[ks * 32 + quad * 8];
  }

  // staging with 512 threads: K 64x96 = 768 slots; V 80x64 = 640 slots
  short8 kreg[2], vreg[2];
#define PREFETCH(c)                                                        \
  {                                                                        \
    {                                                                      \
      int row = t / 12, col = (t % 12) * 8;                                \
      kreg[0] = *(const short8*)&Kb[(size_t)((c) + row) * HDP + col];      \
    }                                                                      \
    if (t < 256) {                                                         \
      int idx = 512 + t;                                                   \
      int row = idx / 12, col = (idx % 12) * 8;                            \
      kreg[1] = *(const short8*)&Kb[(size_t)((c) + row) * HDP + col];      \
    }                                                                      \
    {                                                                      \
      int d = t >> 3, s0 = (t & 7) * 8;                                    \
      vreg[0] = *(const short8*)&Vb[(size_t)d * 1024 + (c) + s0];          \
    }                                                                      \
    if (t < 128) {                                                         \
      int idx = 512 + t;                                                   \
      int d = idx >> 3, s0 = (idx & 7) * 8;                                \
      vreg[1] = *(const short8*)&Vb[(size_t)d * 1024 + (c) + s0];          \
    }                                                                      \
  }
#define STORE_LDS(P)                                                       \
  {                                                                        \
    {                                                                      \
      int row = t / 12, col = (t % 12) * 8;                                \
      *(short8*)&Klds[P][row * 104 + col] = kreg[0];                       \
    }                                                                      \
    if (t < 256) {                                                         \
      int idx = 512 + t;                                                   \
      int row = idx / 12, col = (idx % 12) * 8;                            \
      *(short8*)&Klds[P][row * 104 + col] = kreg[1];                       \
    }                                                                      \
    {                                                                      \
      int d = t >> 3, s0 = (t & 7) * 8;                                    \
      *(short8*)&Vlds[P][d * 72 + s0] = vreg[0];                           \
    }                                                                      \
    if (t < 128) {                                                         \
      int idx = 512 + t;                                                   \
      int d = idx >> 3, s0 = (idx & 7) * 8;                                \
      *(short8*)&Vlds[P][d * 72 + s0] = vreg[1];                           \
    }                                                                      \
  }

  PREFETCH(0);
  STORE_LDS(0);
  __syncthreads();

  f32x4 ofr[5] = {};
  float lsum = 0.f;

  int p = 0;
  for (int c = 0; c < 1024; c += 64, p ^= 1) {
    if (c + 64 < 1024) PREFETCH(c + 64);   // global loads fly under compute
    const short* Kl = &Klds[p][0];
    const short* Vl = &Vlds[p][0];
    // swapped QK^T: S^T(64kv x 16q) per wave; sf[nt] covers kv nt*16..+15
    f32x4 sf[4] = {};
#pragma unroll
    for (int nt = 0; nt < 4; nt++) {
      short8 bk0 = *(const short8*)&Kl[(nt * 16 + l16) * 104 + 0 * 32 + quad * 8];
      short8 bk1 = *(const short8*)&Kl[(nt * 16 + l16) * 104 + 1 * 32 + quad * 8];
      short8 bk2 = *(const short8*)&Kl[(nt * 16 + l16) * 104 + 2 * 32 + quad * 8];
      sf[nt] = MFMA(bk0, aq[0], sf[nt]);   // A=K (rows kv), B=Q (cols q)
      sf[nt] = MFMA(bk1, aq[1], sf[nt]);
      sf[nt] = MFMA(bk2, aq[2], sf[nt]);
    }
    // unsafe softmax in-register: lane holds P[kv=nt*16+quad*4+r][q=l16]
    short4v bp[4];
#pragma unroll
    for (int nt = 0; nt < 4; nt++) {
      float e0 = __expf(fminf(sf[nt][0], 30.f));
      float e1 = __expf(fminf(sf[nt][1], 30.f));
      float e2 = __expf(fminf(sf[nt][2], 30.f));
      float e3 = __expf(fminf(sf[nt][3], 30.f));
      lsum += (e0 + e1) + (e2 + e3);
      bp[nt][0] = f2b(e0); bp[nt][1] = f2b(e1);
      bp[nt][2] = f2b(e2); bp[nt][3] = f2b(e3);
    }
    // PV as O^T = V^T * P: 4 kv-steps (k=16) x 5 d-blocks, P from registers
#pragma unroll
    for (int cc = 0; cc < 4; cc++)
#pragma unroll
      for (int nt5 = 0; nt5 < 5; nt5++) {
        short4v va =
            *(const short4v*)&Vl[(nt5 * 16 + l16) * 72 + cc * 16 + quad * 4];
        ofr[nt5] = MFMA16(va, bp[cc], ofr[nt5]);
      }
    if (c + 64 < 1024) {
      STORE_LDS(p ^ 1);       // idle buffer; readers of it passed last barrier
      __syncthreads();        // publish + close this iter's reads of buf p
    }
  }
  // row sum: partials for q=l16 live in the 4 lanes sharing l16 (xor 16,32)
  lsum += __shfl_xor(lsum, 16);
  lsum += __shfl_xor(lsum, 32);
  float inv = 1.f / lsum;
  int b = bh >> 4, h = bh & 15;
  int s = q0 + w * 16 + l16;
#pragma unroll
  for (int nt5 = 0; nt5 < 5; nt5++) {
    short4v o;
#pragma unroll
    for (int j = 0; j < 4; j++) o[j] = f2b(ofr[nt5][j] * inv);
    *(short4v*)&out[((size_t)(b * 1024 + s)) * 1280 + h * 80 + nt5 * 16 +
                    quad * 4] = o;
  }
}

// ---------------------------------------------------------------- proj GEMM
__global__ __launch_bounds__(256) void gemm_proj_kernel(
    const short* __restrict__ A, const short* __restrict__ Wt,
    const void* __restrict__ bias, const unsigned* __restrict__ probe,
    float* __restrict__ out) {
  const int K = 1280;
  __shared__ short As[2][128 * 32];
  __shared__ short Bs[2][128 * 32];
  int t = threadIdx.x;
  int bm = blockIdx.x / 10;
  int bn = blockIdx.x % 10;
  int m0 = bm * 128, n0 = bn * 128;
  int w = t >> 6, lane = t & 63;
  int wm = w & 1, wn = w >> 1;
  int quad = lane >> 4, l16 = lane & 15;
  int row = t >> 2, ch = (t & 3) * 8, row2 = row + 64;
  int t8 = t * 8;
  const short* Ar  = A  + (size_t)(m0 + row)  * K + ch;
  const short* Ar2 = A  + (size_t)(m0 + row2) * K + ch;
  const short* Wr  = Wt + (size_t)(n0 + row)  * K + ch;
  const short* Wr2 = Wt + (size_t)(n0 + row2) * K + ch;
  f32x4 acc[4][4] = {};
  gload_lds16(Ar,  &As[0][t8]);
  gload_lds16(Ar2, &As[0][t8 + 2048]);
  gload_lds16(Wr,  &Bs[0][t8]);
  gload_lds16(Wr2, &Bs[0][t8 + 2048]);
  __syncthreads();
  int p = 0;
#define PROJ_COMPUTE(pp)                                                      \
  {                                                                           \
    short8 af[4], bfr[4];                                                     \
    _Pragma("unroll") for (int mt = 0; mt < 4; mt++)                          \
        af[mt] = *(const short8*)&As[pp][(wm * 64 + mt * 16 + l16) * 32 + quad * 8]; \
    _Pragma("unroll") for (int nt = 0; nt < 4; nt++)                          \
        bfr[nt] = *(const short8*)&Bs[pp][(wn * 64 + nt * 16 + l16) * 32 + quad * 8]; \
    _Pragma("unroll") for (int mt = 0; mt < 4; mt++)                          \
        _Pragma("unroll") for (int nt = 0; nt < 4; nt++)                      \
            acc[mt][nt] = MFMA(af[mt], bfr[nt], acc[mt][nt]);                 \
  }
  for (int k0 = 32; k0 < K; k0 += 32, p ^= 1) {
    gload_lds16(Ar + k0,  &As[p ^ 1][t8]);
    gload_lds16(Ar2 + k0, &As[p ^ 1][t8 + 2048]);
    gload_lds16(Wr + k0,  &Bs[p ^ 1][t8]);
    gload_lds16(Wr2 + k0, &Bs[p ^ 1][t8 + 2048]);
    PROJ_COMPUTE(p);
    __syncthreads();
  }
  PROJ_COMPUTE(p);
  bool isb = probe_is_bf16(probe);
  float bv[4];
#pragma unroll
  for (int nt = 0; nt < 4; nt++)
    bv[nt] = load_scalar(bias, n0 + wn * 64 + nt * 16 + l16, isb);
#pragma unroll
  for (int mt = 0; mt < 4; mt++) {
#pragma unroll
    for (int nt = 0; nt < 4; nt++) {
      int n = n0 + wn * 64 + nt * 16 + l16;
#pragma unroll
      for (int reg = 0; reg < 4; reg++) {
        int m = m0 + wm * 64 + mt * 16 + quad * 4 + reg;
        out[(size_t)m * 1280 + n] = acc[mt][nt][reg] + bv[nt];  // FP32 store
      }
    }
  }
}

extern "C" void kernel_launch(void* const* d_in, const int* in_sizes, int n_in,
                              void* d_out, int out_size, void* d_ws, size_t ws_size,
                              hipStream_t stream) {
  const void* x        = d_in[0];
  const void* rope_cos = d_in[1];
  const void* rope_sin = d_in[2];
  const void* Wqkv     = d_in[3];
  const void* bqkv     = d_in[4];
  const void* Wproj    = d_in[5];
  const void* bproj    = d_in[6];
  const unsigned* probe = (const unsigned*)rope_cos;
  char* ws = (char*)d_ws;
  short* Wt1 = (short*)(ws + 0);          // 1280*3840*2 = 9,830,400
  short* Wt2 = (short*)(ws + 9830400);    // 1280*1280*2 = 3,276,800
  short* Qw  = (short*)(ws + 13107200);   // 64*1024*96*2 = 12,582,912
  short* Kw  = (short*)(ws + 25690112);   // 12,582,912
  short* Vt  = (short*)(ws + 38273024);   // 64*1024*80*2 = 10,485,760
  short* Xb  = (short*)(ws + 48758784);   // 4096*1280*2 = 10,485,760
  short* At  = (short*)(ws + 48758784);   // aliases Xb (disjoint lifetimes)

  cvt_x_kernel<<<2560, 256, 0, stream>>>(x, Xb, probe);
  transpose_kernel<<<dim3(3840 / 32, 1280 / 32), 256, 0, stream>>>(Wqkv, Wt1, 1280, 3840, probe);
  transpose_kernel<<<dim3(1280 / 32, 1280 / 32), 256, 0, stream>>>(Wproj, Wt2, 1280, 1280, probe);
  gemm_qkv_kernel<<<240, 512, 0, stream>>>(Xb, Wt1, bqkv, probe, Qw, Kw, Vt);
  rope_kernel<<<32768, 256, 0, stream>>>(Qw, Kw, rope_cos, rope_sin, probe);
  attn_kernel<<<512, 512, 0, stream>>>(Qw, Kw, Vt, At);
  gemm_proj_kernel<<<32 * 10, 256, 0, stream>>>(At, Wt2, bproj, probe, (float*)d_out);
}

// Round 10
// 232.907 us; speedup vs baseline: 1.0896x; 1.0172x over previous
//
#include <hip/hip_runtime.h>
#include <math.h>

// Problem constants: B=4, S=1024, DIM=1280, H=16, HD=80
// Inputs fp32 (runtime-probed); OUTPUT FP32.
#define SCALE_F 0.11180339887498949f   // 80^-0.5
#define HDP 96                          // HD padded to multiple of 32 for QK^T

typedef short  short8  __attribute__((ext_vector_type(8)));
typedef short  short4v __attribute__((ext_vector_type(4)));
typedef float  f32x4   __attribute__((ext_vector_type(4)));
typedef __bf16 bf16x8  __attribute__((ext_vector_type(8)));
typedef __bf16 bf16x4  __attribute__((ext_vector_type(4)));

__device__ __forceinline__ float bf2f(short s) {
  union { unsigned u; float f; } v;
  v.u = ((unsigned)(unsigned short)s) << 16;
  return v.f;
}
__device__ __forceinline__ short f2b(float f) {
  __bf16 h = (__bf16)f;
  return __builtin_bit_cast(short, h);
}
__device__ __forceinline__ bool probe_is_bf16(const unsigned* probe) {
  return (probe[1] & 0xFFFFu) != 0u;
}
__device__ __forceinline__ float load_scalar(const void* p, int i, bool isb) {
  return isb ? bf2f(((const short*)p)[i]) : ((const float*)p)[i];
}

// async global->LDS, 16B per lane. HW LDS placement: wave-uniform base +
// lane*16 (m104/m108); per-lane pointer below coincides with that exactly.
__device__ __forceinline__ void gload_lds16(const short* g, short* l) {
  __builtin_amdgcn_global_load_lds(
      (const __attribute__((address_space(1))) void*)g,
      (__attribute__((address_space(3))) void*)l, 16, 0, 0);
}

template <typename V>
__device__ __forceinline__ auto mfma_try(V a, V b, f32x4 c, int)
    -> decltype(__builtin_amdgcn_mfma_f32_16x16x32_bf16(a, b, c, 0, 0, 0)) {
  return __builtin_amdgcn_mfma_f32_16x16x32_bf16(a, b, c, 0, 0, 0);
}
template <typename V>
__device__ __forceinline__ f32x4 mfma_try(V a, V b, f32x4 c, long) {
  return __builtin_amdgcn_mfma_f32_16x16x32_bf16(
      __builtin_bit_cast(bf16x8, a), __builtin_bit_cast(bf16x8, b), c, 0, 0, 0);
}
__device__ __forceinline__ f32x4 MFMA(short8 a, short8 b, f32x4 c) {
  return mfma_try(a, b, c, 0);
}

// 16x16x16 bf16 MFMA (k=16): A/B = 4 bf16 (2 VGPRs), C/D = f32x4.
// Builtin name varies across ROCm; 3-way guarded.
#if __has_builtin(__builtin_amdgcn_mfma_f32_16x16x16bf16_1k)
template <typename V>
__device__ __forceinline__ auto mfma16_try(V a, V b, f32x4 c, int)
    -> decltype(__builtin_amdgcn_mfma_f32_16x16x16bf16_1k(a, b, c, 0, 0, 0)) {
  return __builtin_amdgcn_mfma_f32_16x16x16bf16_1k(a, b, c, 0, 0, 0);
}
template <typename V>
__device__ __forceinline__ f32x4 mfma16_try(V a, V b, f32x4 c, long) {
  return __builtin_amdgcn_mfma_f32_16x16x16bf16_1k(
      __builtin_bit_cast(bf16x4, a), __builtin_bit_cast(bf16x4, b), c, 0, 0, 0);
}
__device__ __forceinline__ f32x4 MFMA16(short4v a, short4v b, f32x4 c) {
  return mfma16_try(a, b, c, 0);
}
#elif __has_builtin(__builtin_amdgcn_mfma_f32_16x16x16_bf16)
template <typename V>
__device__ __forceinline__ auto mfma16_try(V a, V b, f32x4 c, int)
    -> decltype(__builtin_amdgcn_mfma_f32_16x16x16_bf16(a, b, c, 0, 0, 0)) {
  return __builtin_amdgcn_mfma_f32_16x16x16_bf16(a, b, c, 0, 0, 0);
}
template <typename V>
__device__ __forceinline__ f32x4 mfma16_try(V a, V b, f32x4 c, long) {
  return __builtin_amdgcn_mfma_f32_16x16x16_bf16(
      __builtin_bit_cast(bf16x4, a), __builtin_bit_cast(bf16x4, b), c, 0, 0, 0);
}
__device__ __forceinline__ f32x4 MFMA16(short4v a, short4v b, f32x4 c) {
  return mfma16_try(a, b, c, 0);
}
#else
__device__ __forceinline__ f32x4 MFMA16(short4v a, short4v b, f32x4 c) {
  asm volatile("v_mfma_f32_16x16x16_bf16 %0, %1, %2, %0"
               : "+v"(c) : "v"(a), "v"(b));
  return c;
}
#endif

// ------------------------------------------------------- canonicalize: x->bf16
__global__ __launch_bounds__(256) void cvt_x_kernel(
    const void* __restrict__ xin, short* __restrict__ xout,
    const unsigned* __restrict__ probe) {
  bool isb = probe_is_bf16(probe);
  size_t i = ((size_t)blockIdx.x * 256 + threadIdx.x) * 8;
  if (isb) {
    *(short8*)&xout[i] = *(const short8*)((const short*)xin + i);
  } else {
    const float* f = (const float*)xin + i;
    float4 a0 = *(const float4*)f;
    float4 a1 = *(const float4*)(f + 4);
    short8 sv;
    sv[0] = f2b(a0.x); sv[1] = f2b(a0.y); sv[2] = f2b(a0.z); sv[3] = f2b(a0.w);
    sv[4] = f2b(a1.x); sv[5] = f2b(a1.y); sv[6] = f2b(a1.z); sv[7] = f2b(a1.w);
    *(short8*)&xout[i] = sv;
  }
}

// ---------------------------------------------------------------- transpose
__global__ __launch_bounds__(256) void transpose_kernel(
    const void* __restrict__ in, short* __restrict__ out, int R, int C,
    const unsigned* __restrict__ probe) {
  bool isb = probe_is_bf16(probe);
  __shared__ float tile[32][33];
  int t = threadIdx.x;
  int bx = blockIdx.x;  // over C
  int by = blockIdx.y;  // over R
  int r = t >> 3, c4 = (t & 7) * 4;
  size_t idx = (size_t)(by * 32 + r) * C + bx * 32 + c4;
  if (isb) {
    short4v v = *(const short4v*)((const short*)in + idx);
    tile[r][c4 + 0] = bf2f(v[0]);
    tile[r][c4 + 1] = bf2f(v[1]);
    tile[r][c4 + 2] = bf2f(v[2]);
    tile[r][c4 + 3] = bf2f(v[3]);
  } else {
    float4 v = *(const float4*)((const float*)in + idx);
    tile[r][c4 + 0] = v.x;
    tile[r][c4 + 1] = v.y;
    tile[r][c4 + 2] = v.z;
    tile[r][c4 + 3] = v.w;
  }
  __syncthreads();
  int rr = t >> 3, k4 = (t & 7) * 4;
  short4v o;
  o[0] = f2b(tile[k4 + 0][rr]);
  o[1] = f2b(tile[k4 + 1][rr]);
  o[2] = f2b(tile[k4 + 2][rr]);
  o[3] = f2b(tile[k4 + 3][rr]);
  *(short4v*)&out[(size_t)(bx * 32 + rr) * R + by * 32 + k4] = o;
}

// ---------------------------------------------------------------- QKV GEMM
// r8 structure (verified): 256x256, BK=64, 8 waves, 8-phase, T2 swizzle
// (0 conflicts), counted vmcnt at ph3/ph7, 1 barrier/phase, register-hoisted
// A/B fragments.
__global__ __launch_bounds__(512, 2) void gemm_qkv_kernel(
    const short* __restrict__ X, const short* __restrict__ Wt,
    const void* __restrict__ bias, const unsigned* __restrict__ probe,
    short* __restrict__ Qw, short* __restrict__ Kw, short* __restrict__ Vt) {
  const int K = 1280;
  __shared__ short Al[2][2][8192];   // [slot][half][128*64]
  __shared__ short Bl[2][2][8192];
  int t = threadIdx.x;
  int bm = blockIdx.x / 15, bn = blockIdx.x % 15;
  int m0 = bm * 256, n0 = bn * 256;
  int w = t >> 6, lane = t & 63;
  int quad = lane >> 4, l16 = lane & 15, l8 = l16 & 7;
  int arow = (w >> 2) * 64 + l16;   // + mt*16 -> A row within half
  int brow = (w & 3) * 32 + l16;    // + nt*16 -> B row within half
  int sr = t >> 3, t8s = t * 8;
  int sjs = (t & 7) ^ (sr & 7);     // pre-swizzled global k-slot (involution)
  int soff0 = ((quad ^ l8) * 8);
  int soff1 = (((4 + quad) ^ l8) * 8);
  f32x4 acc[2][2][4][2] = {};       // [qm][qn][mt][nt], all-static indexing
  short8 afr[4][2];                 // A fragments of current (S,HA)
  short8 bf0[2][2], bf1[2][2];      // B fragments, half0 / half1 of current S

#define STAGE8(PTR, R0, KOFF, LP)                                            \
  {                                                                          \
    const short* g_ = (PTR) + (size_t)((R0) + sr) * 1280 + (KOFF) + sjs * 8; \
    gload_lds16(g_, (LP) + t8s);                                             \
    gload_lds16(g_ + 64 * 1280, (LP) + t8s + 4096);                          \
  }

#define READ_A(S, H)                                                         \
  {                                                                          \
    _Pragma("unroll") for (int mt = 0; mt < 4; mt++) {                       \
      int rp_ = (arow + mt * 16) * 64;                                       \
      afr[mt][0] = *(const short8*)&Al[S][H][rp_ + soff0];                   \
      afr[mt][1] = *(const short8*)&Al[S][H][rp_ + soff1];                   \
    }                                                                        \
  }
#define READ_B(DST, S, H)                                                    \
  {                                                                          \
    _Pragma("unroll") for (int nt = 0; nt < 2; nt++) {                       \
      int rp_ = (brow + nt * 16) * 64;                                       \
      DST[nt][0] = *(const short8*)&Bl[S][H][rp_ + soff0];                   \
      DST[nt][1] = *(const short8*)&Bl[S][H][rp_ + soff1];                   \
    }                                                                        \
  }
#define MFMA16C(QM, QN, BF, WAITI)                                           \
  {                                                                          \
    asm volatile("s_waitcnt lgkmcnt(" #WAITI ")" ::: "memory");              \
    __builtin_amdgcn_sched_barrier(0);                                       \
    __builtin_amdgcn_s_setprio(1);                                           \
    _Pragma("unroll") for (int mt = 0; mt < 4; mt++)                         \
      _Pragma("unroll") for (int nt = 0; nt < 2; nt++) {                     \
        acc[QM][QN][mt][nt] = MFMA(afr[mt][0], BF[nt][0], acc[QM][QN][mt][nt]); \
        acc[QM][QN][mt][nt] = MFMA(afr[mt][1], BF[nt][1], acc[QM][QN][mt][nt]); \
      }                                                                      \
    __builtin_amdgcn_s_setprio(0);                                           \
  }
#define BAR() __builtin_amdgcn_s_barrier()
#define VW4()                                                                \
  {                                                                          \
    asm volatile("s_waitcnt vmcnt(4)" ::: "memory");                         \
    __builtin_amdgcn_sched_barrier(0);                                       \
  }

  // prologue: tile0 (all 4 halves) + tile1 (A0,B0) = 12 loads/thread
  STAGE8(X,  m0,       0,  &Al[0][0][0]);
  STAGE8(X,  m0 + 128, 0,  &Al[0][1][0]);
  STAGE8(Wt, n0,       0,  &Bl[0][0][0]);
  STAGE8(Wt, n0 + 128, 0,  &Bl[0][1][0]);
  STAGE8(X,  m0,       64, &Al[1][0][0]);
  STAGE8(Wt, n0,       64, &Bl[1][0][0]);
  VW4();   // tile0's 8 loads landed
  BAR();

  for (int i = 0; i < 10; i++) {
    int k1 = (2 * i + 1) * 64;                       // <= 1216, always valid
    int k2 = (2 * i + 2) * 64; if (k2 >= K) k2 = 0;  // dummy (unread) on tail
    int k3 = (2 * i + 3) * 64; if (k3 >= K) k3 = 0;
    // ---- S=0 group ----
    READ_A(0, 0); READ_B(bf0, 0, 0); READ_B(bf1, 0, 1);   // 16 reads
    STAGE8(X,  m0 + 128, k1, &Al[1][1][0]);
    MFMA16C(0, 0, bf0, 4);   // bf1's 4 reads land under the MFMAs
    BAR();                                                        // ph0
    STAGE8(Wt, n0 + 128, k1, &Bl[1][1][0]);
    MFMA16C(0, 1, bf1, 0);
    BAR();                                                        // ph1
    READ_A(0, 1);                                          // 8 reads
    STAGE8(X,  m0,       k2, &Al[0][0][0]);
    MFMA16C(1, 0, bf0, 0);
    BAR();                                                        // ph2
    STAGE8(Wt, n0,       k2, &Bl[0][0][0]);
    MFMA16C(1, 1, bf1, 0);
    VW4();
    BAR();                                                        // ph3
    // ---- S=1 group ----
    READ_A(1, 0); READ_B(bf0, 1, 0); READ_B(bf1, 1, 1);
    STAGE8(X,  m0 + 128, k2, &Al[0][1][0]);
    MFMA16C(0, 0, bf0, 4);
    BAR();                                                        // ph4
    STAGE8(Wt, n0 + 128, k2, &Bl[0][1][0]);
    MFMA16C(0, 1, bf1, 0);
    BAR();                                                        // ph5
    READ_A(1, 1);
    STAGE8(X,  m0,       k3, &Al[1][0][0]);
    MFMA16C(1, 0, bf0, 0);
    BAR();                                                        // ph6
    STAGE8(Wt, n0,       k3, &Bl[1][0][0]);
    MFMA16C(1, 1, bf1, 0);
    VW4();
    BAR();                                                        // ph7
  }
  asm volatile("s_waitcnt vmcnt(0)" ::: "memory");   // drain dummy stages
  __builtin_amdgcn_sched_barrier(0);

  bool isb = probe_is_bf16(probe);
  float bv[2][2];
#pragma unroll
  for (int qn = 0; qn < 2; qn++)
#pragma unroll
    for (int nt = 0; nt < 2; nt++)
      bv[qn][nt] =
          load_scalar(bias, n0 + qn * 128 + (w & 3) * 32 + nt * 16 + l16, isb);
#pragma unroll
  for (int qm = 0; qm < 2; qm++)
#pragma unroll
    for (int mt = 0; mt < 4; mt++) {
      int mbase = m0 + qm * 128 + (w >> 2) * 64 + mt * 16 + quad * 4;
      int b = mbase >> 10, sbase = mbase & 1023;
#pragma unroll
      for (int qn = 0; qn < 2; qn++)
#pragma unroll
        for (int nt = 0; nt < 2; nt++) {
          int n = n0 + qn * 128 + (w & 3) * 32 + nt * 16 + l16;
          int which = n / 1280;
          int rmod = n - which * 1280;
          int h = rmod / 80;
          int d = rmod - h * 80;
          int bh = b * 16 + h;
          if (which == 2) {
            short4v vv;
#pragma unroll
            for (int reg = 0; reg < 4; reg++)
              vv[reg] = f2b(acc[qm][qn][mt][nt][reg] + bv[qn][nt]);
            *(short4v*)&Vt[((size_t)bh * 80 + d) * 1024 + sbase] = vv;
          } else {
            short* dst = (which == 0 ? Qw : Kw);
#pragma unroll
            for (int reg = 0; reg < 4; reg++)
              dst[((size_t)bh * 1024 + sbase + reg) * HDP + d] =
                  f2b(acc[qm][qn][mt][nt][reg] + bv[qn][nt]);
          }
        }
    }
#undef STAGE8
#undef READ_A
#undef READ_B
#undef MFMA16C
#undef BAR
#undef VW4
}

// ---------------------------------------------------------------- RoPE
// r10: vectorized (G13). rotate-half pairs d and d+40; 40 % 8 == 0, so each
// thread owns the 8-elem chunk pair (d0=p*8, d1=40+p*8), p in [0,5): two
// short8 loads + two short8 stores per thread, vector cos/sin loads (fp32
// float4 x2 or bf16 short8). Each chunk is read+written by exactly ONE
// thread -> no cross-thread hazard. p==0 also zeroes the d=80..95 pad.
__global__ __launch_bounds__(256) void rope_kernel(
    short* __restrict__ Qw, short* __restrict__ Kw,
    const void* __restrict__ cosb, const void* __restrict__ sinb,
    const unsigned* __restrict__ probe) {
  bool isb = probe_is_bf16(probe);
  int tg = blockIdx.x * 256 + threadIdx.x;   // 0..655359
  int row_all = tg / 5;                      // 0..131071
  int p = tg - row_all * 5;                  // 0..4
  int which = row_all >> 16;                 // 0 = Q, 1 = K
  int r = row_all & 65535;                   // bh*1024 + s
  int s = r & 1023;
  short* ptr = (which ? Kw : Qw) + (size_t)r * HDP;
  float scale = which ? 1.0f : SCALE_F;
  int d0 = p * 8, d1 = 40 + p * 8;
  short8 a = *(const short8*)&ptr[d0];
  short8 b = *(const short8*)&ptr[d1];
  float c0[8], s0[8], c1[8], s1[8];
  if (isb) {
    const short* cb = (const short*)cosb + s * 80;
    const short* sb = (const short*)sinb + s * 80;
    short8 vc0 = *(const short8*)&cb[d0];
    short8 vs0 = *(const short8*)&sb[d0];
    short8 vc1 = *(const short8*)&cb[d1];
    short8 vs1 = *(const short8*)&sb[d1];
#pragma unroll
    for (int j = 0; j < 8; j++) {
      c0[j] = bf2f(vc0[j]); s0[j] = bf2f(vs0[j]);
      c1[j] = bf2f(vc1[j]); s1[j] = bf2f(vs1[j]);
    }
  } else {
    const float* cb = (const float*)cosb + s * 80;
    const float* sb = (const float*)sinb + s * 80;
    float4 vc0a = *(const float4*)&cb[d0];
    float4 vc0b = *(const float4*)&cb[d0 + 4];
    float4 vs0a = *(const float4*)&sb[d0];
    float4 vs0b = *(const float4*)&sb[d0 + 4];
    float4 vc1a = *(const float4*)&cb[d1];
    float4 vc1b = *(const float4*)&cb[d1 + 4];
    float4 vs1a = *(const float4*)&sb[d1];
    float4 vs1b = *(const float4*)&sb[d1 + 4];
    c0[0] = vc0a.x; c0[1] = vc0a.y; c0[2] = vc0a.z; c0[3] = vc0a.w;
    c0[4] = vc0b.x; c0[5] = vc0b.y; c0[6] = vc0b.z; c0[7] = vc0b.w;
    s0[0] = vs0a.x; s0[1] = vs0a.y; s0[2] = vs0a.z; s0[3] = vs0a.w;
    s0[4] = vs0b.x; s0[5] = vs0b.y; s0[6] = vs0b.z; s0[7] = vs0b.w;
    c1[0] = vc1a.x; c1[1] = vc1a.y; c1[2] = vc1a.z; c1[3] = vc1a.w;
    c1[4] = vc1b.x; c1[5] = vc1b.y; c1[6] = vc1b.z; c1[7] = vc1b.w;
    s1[0] = vs1a.x; s1[1] = vs1a.y; s1[2] = vs1a.z; s1[3] = vs1a.w;
    s1[4] = vs1b.x; s1[5] = vs1b.y; s1[6] = vs1b.z; s1[7] = vs1b.w;
  }
  short8 o0, o1;
#pragma unroll
  for (int j = 0; j < 8; j++) {
    float av = bf2f(a[j]), bv = bf2f(b[j]);
    o0[j] = f2b((av * c0[j] - bv * s0[j]) * scale);
    o1[j] = f2b((bv * c1[j] + av * s1[j]) * scale);
  }
  *(short8*)&ptr[d0] = o0;
  *(short8*)&ptr[d1] = o1;
  if (p == 0) {
    short8 z = {};
    *(short8*)&ptr[80] = z;
    *(short8*)&ptr[88] = z;
  }
}

// ---------------------------------------------------------------- attention
// r9 (verified): swapped QK^T -> P stays in registers; double-buffered K/V,
// one barrier per chunk.
__global__ __launch_bounds__(512, 4) void attn_kernel(
    const short* __restrict__ Qw, const short* __restrict__ Kw,
    const short* __restrict__ Vt, short* __restrict__ out) {
  __shared__ short Klds[2][64 * 104];
  __shared__ short Vlds[2][80 * 72];
  int t = threadIdx.x;
  int w = t >> 6, lane = t & 63;
  int quad = lane >> 4, l16 = lane & 15;
  int bh = blockIdx.x & 63;        // XCD swizzle: same bh -> same XCD
  int qt = blockIdx.x >> 6;        // 0..7
  int q0 = qt * 128;
  const short* Kb = Kw + (size_t)bh * 1024 * HDP;
  const short* Vb = Vt + (size_t)bh * 80 * 1024;

  short8 aq[3];
  {
    const short* qrow = Qw + ((size_t)bh * 1024 + q0 + w * 16 + l16) * HDP;
#pragma unroll
    for (int ks = 0; ks < 3; ks++)
      aq[ks] = *(const short8*)&qrow[ks * 32 + quad * 8];
  }

  short8 kreg[2], vreg[2];
#define PREFETCH(c)                                                        \
  {                                                                        \
    {                                                                      \
      int row = t / 12, col = (t % 12) * 8;                                \
      kreg[0] = *(const short8*)&Kb[(size_t)((c) + row) * HDP + col];      \
    }                                                                      \
    if (t < 256) {                                                         \
      int idx = 512 + t;                                                   \
      int row = idx / 12, col = (idx % 12) * 8;                            \
      kreg[1] = *(const short8*)&Kb[(size_t)((c) + row) * HDP + col];      \
    }                                                                      \
    {                                                                      \
      int d = t >> 3, s0 = (t & 7) * 8;                                    \
      vreg[0] = *(const short8*)&Vb[(size_t)d * 1024 + (c) + s0];          \
    }                                                                      \
    if (t < 128) {                                                         \
      int idx = 512 + t;                                                   \
      int d = idx >> 3, s0 = (idx & 7) * 8;                                \
      vreg[1] = *(const short8*)&Vb[(size_t)d * 1024 + (c) + s0];          \
    }                                                                      \
  }
#define STORE_LDS(P)                                                       \
  {                                                                        \
    {                                                                      \
      int row = t / 12, col = (t % 12) * 8;                                \
      *(short8*)&Klds[P][row * 104 + col] = kreg[0];                       \
    }                                                                      \
    if (t < 256) {                                                         \
      int idx = 512 + t;                                                   \
      int row = idx / 12, col = (idx % 12) * 8;                            \
      *(short8*)&Klds[P][row * 104 + col] = kreg[1];                       \
    }                                                                      \
    {                                                                      \
      int d = t >> 3, s0 = (t & 7) * 8;                                    \
      *(short8*)&Vlds[P][d * 72 + s0] = vreg[0];                           \
    }                                                                      \
    if (t < 128) {                                                         \
      int idx = 512 + t;                                                   \
      int d = idx >> 3, s0 = (idx & 7) * 8;                                \
      *(short8*)&Vlds[P][d * 72 + s0] = vreg[1];                           \
    }                                                                      \
  }

  PREFETCH(0);
  STORE_LDS(0);
  __syncthreads();

  f32x4 ofr[5] = {};
  float lsum = 0.f;

  int p = 0;
  for (int c = 0; c < 1024; c += 64, p ^= 1) {
    if (c + 64 < 1024) PREFETCH(c + 64);   // global loads fly under compute
    const short* Kl = &Klds[p][0];
    const short* Vl = &Vlds[p][0];
    f32x4 sf[4] = {};
#pragma unroll
    for (int nt = 0; nt < 4; nt++) {
      short8 bk0 = *(const short8*)&Kl[(nt * 16 + l16) * 104 + 0 * 32 + quad * 8];
      short8 bk1 = *(const short8*)&Kl[(nt * 16 + l16) * 104 + 1 * 32 + quad * 8];
      short8 bk2 = *(const short8*)&Kl[(nt * 16 + l16) * 104 + 2 * 32 + quad * 8];
      sf[nt] = MFMA(bk0, aq[0], sf[nt]);   // A=K (rows kv), B=Q (cols q)
      sf[nt] = MFMA(bk1, aq[1], sf[nt]);
      sf[nt] = MFMA(bk2, aq[2], sf[nt]);
    }
    short4v bp[4];
#pragma unroll
    for (int nt = 0; nt < 4; nt++) {
      float e0 = __expf(fminf(sf[nt][0], 30.f));
      float e1 = __expf(fminf(sf[nt][1], 30.f));
      float e2 = __expf(fminf(sf[nt][2], 30.f));
      float e3 = __expf(fminf(sf[nt][3], 30.f));
      lsum += (e0 + e1) + (e2 + e3);
      bp[nt][0] = f2b(e0); bp[nt][1] = f2b(e1);
      bp[nt][2] = f2b(e2); bp[nt][3] = f2b(e3);
    }
#pragma unroll
    for (int cc = 0; cc < 4; cc++)
#pragma unroll
      for (int nt5 = 0; nt5 < 5; nt5++) {
        short4v va =
            *(const short4v*)&Vl[(nt5 * 16 + l16) * 72 + cc * 16 + quad * 4];
        ofr[nt5] = MFMA16(va, bp[cc], ofr[nt5]);
      }
    if (c + 64 < 1024) {
      STORE_LDS(p ^ 1);       // idle buffer; readers of it passed last barrier
      __syncthreads();        // publish + close this iter's reads of buf p
    }
  }
  lsum += __shfl_xor(lsum, 16);
  lsum += __shfl_xor(lsum, 32);
  float inv = 1.f / lsum;
  int b = bh >> 4, h = bh & 15;
  int s = q0 + w * 16 + l16;
#pragma unroll
  for (int nt5 = 0; nt5 < 5; nt5++) {
    short4v o;
#pragma unroll
    for (int j = 0; j < 4; j++) o[j] = f2b(ofr[nt5][j] * inv);
    *(short4v*)&out[((size_t)(b * 1024 + s)) * 1280 + h * 80 + nt5 * 16 +
                    quad * 4] = o;
  }
}

// ---------------------------------------------------------------- proj GEMM
__global__ __launch_bounds__(256) void gemm_proj_kernel(
    const short* __restrict__ A, const short* __restrict__ Wt,
    const void* __restrict__ bias, const unsigned* __restrict__ probe,
    float* __restrict__ out) {
  const int K = 1280;
  __shared__ short As[2][128 * 32];
  __shared__ short Bs[2][128 * 32];
  int t = threadIdx.x;
  int bm = blockIdx.x / 10;
  int bn = blockIdx.x % 10;
  int m0 = bm * 128, n0 = bn * 128;
  int w = t >> 6, lane = t & 63;
  int wm = w & 1, wn = w >> 1;
  int quad = lane >> 4, l16 = lane & 15;
  int row = t >> 2, ch = (t & 3) * 8, row2 = row + 64;
  int t8 = t * 8;
  const short* Ar  = A  + (size_t)(m0 + row)  * K + ch;
  const short* Ar2 = A  + (size_t)(m0 + row2) * K + ch;
  const short* Wr  = Wt + (size_t)(n0 + row)  * K + ch;
  const short* Wr2 = Wt + (size_t)(n0 + row2) * K + ch;
  f32x4 acc[4][4] = {};
  gload_lds16(Ar,  &As[0][t8]);
  gload_lds16(Ar2, &As[0][t8 + 2048]);
  gload_lds16(Wr,  &Bs[0][t8]);
  gload_lds16(Wr2, &Bs[0][t8 + 2048]);
  __syncthreads();
  int p = 0;
#define PROJ_COMPUTE(pp)                                                      \
  {                                                                           \
    short8 af[4], bfr[4];                                                     \
    _Pragma("unroll") for (int mt = 0; mt < 4; mt++)                          \
        af[mt] = *(const short8*)&As[pp][(wm * 64 + mt * 16 + l16) * 32 + quad * 8]; \
    _Pragma("unroll") for (int nt = 0; nt < 4; nt++)                          \
        bfr[nt] = *(const short8*)&Bs[pp][(wn * 64 + nt * 16 + l16) * 32 + quad * 8]; \
    _Pragma("unroll") for (int mt = 0; mt < 4; mt++)                          \
        _Pragma("unroll") for (int nt = 0; nt < 4; nt++)                      \
            acc[mt][nt] = MFMA(af[mt], bfr[nt], acc[mt][nt]);                 \
  }
  for (int k0 = 32; k0 < K; k0 += 32, p ^= 1) {
    gload_lds16(Ar + k0,  &As[p ^ 1][t8]);
    gload_lds16(Ar2 + k0, &As[p ^ 1][t8 + 2048]);
    gload_lds16(Wr + k0,  &Bs[p ^ 1][t8]);
    gload_lds16(Wr2 + k0, &Bs[p ^ 1][t8 + 2048]);
    PROJ_COMPUTE(p);
    __syncthreads();
  }
  PROJ_COMPUTE(p);
  bool isb = probe_is_bf16(probe);
  float bv[4];
#pragma unroll
  for (int nt = 0; nt < 4; nt++)
    bv[nt] = load_scalar(bias, n0 + wn * 64 + nt * 16 + l16, isb);
#pragma unroll
  for (int mt = 0; mt < 4; mt++) {
#pragma unroll
    for (int nt = 0; nt < 4; nt++) {
      int n = n0 + wn * 64 + nt * 16 + l16;
#pragma unroll
      for (int reg = 0; reg < 4; reg++) {
        int m = m0 + wm * 64 + mt * 16 + quad * 4 + reg;
        out[(size_t)m * 1280 + n] = acc[mt][nt][reg] + bv[nt];  // FP32 store
      }
    }
  }
}

extern "C" void kernel_launch(void* const* d_in, const int* in_sizes, int n_in,
                              void* d_out, int out_size, void* d_ws, size_t ws_size,
                              hipStream_t stream) {
  const void* x        = d_in[0];
  const void* rope_cos = d_in[1];
  const void* rope_sin = d_in[2];
  const void* Wqkv     = d_in[3];
  const void* bqkv     = d_in[4];
  const void* Wproj    = d_in[5];
  const void* bproj    = d_in[6];
  const unsigned* probe = (const unsigned*)rope_cos;
  char* ws = (char*)d_ws;
  short* Wt1 = (short*)(ws + 0);          // 1280*3840*2 = 9,830,400
  short* Wt2 = (short*)(ws + 9830400);    // 1280*1280*2 = 3,276,800
  short* Qw  = (short*)(ws + 13107200);   // 64*1024*96*2 = 12,582,912
  short* Kw  = (short*)(ws + 25690112);   // 12,582,912
  short* Vt  = (short*)(ws + 38273024);   // 64*1024*80*2 = 10,485,760
  short* Xb  = (short*)(ws + 48758784);   // 4096*1280*2 = 10,485,760
  short* At  = (short*)(ws + 48758784);   // aliases Xb (disjoint lifetimes)

  cvt_x_kernel<<<2560, 256, 0, stream>>>(x, Xb, probe);
  transpose_kernel<<<dim3(3840 / 32, 1280 / 32), 256, 0, stream>>>(Wqkv, Wt1, 1280, 3840, probe);
  transpose_kernel<<<dim3(1280 / 32, 1280 / 32), 256, 0, stream>>>(Wproj, Wt2, 1280, 1280, probe);
  gemm_qkv_kernel<<<240, 512, 0, stream>>>(Xb, Wt1, bqkv, probe, Qw, Kw, Vt);
  rope_kernel<<<2560, 256, 0, stream>>>(Qw, Kw, rope_cos, rope_sin, probe);
  attn_kernel<<<512, 512, 0, stream>>>(Qw, Kw, Vt, At);
  gemm_proj_kernel<<<32 * 10, 256, 0, stream>>>(At, Wt2, bproj, probe, (float*)d_out);
}